// Round 9
// baseline (337.341 us; speedup 1.0000x reference)
//
#include <hip/hip_runtime.h>
#include <hip/hip_bf16.h>

typedef unsigned short ushort_t;
typedef __bf16 bf16x8 __attribute__((ext_vector_type(8)));
typedef float f32x4 __attribute__((ext_vector_type(4)));

typedef unsigned int u32;
typedef u32 __attribute__((address_space(1))) global_u32;
typedef u32 __attribute__((address_space(3))) lds_u32;

#define D_ 1024
#define L_ 2048
#define B_ 2
#define H_ 16
#define DH_ 64
#define FF_ 2048
#define ADA_ 6144
#define BHL_ (B_ * H_ * L_)

#define MFMA __builtin_amdgcn_mfma_f32_16x16x32_bf16

__device__ __forceinline__ ushort_t f2bf(float f) {
    union { float f; u32 u; } v; v.f = f;
    u32 r = v.u + 0x7fffu + ((v.u >> 16) & 1u);
    return (ushort_t)(r >> 16);
}

// packed 2xf32 -> 2xbf16 (v_cvt_pk_bf16_f32)
__device__ __forceinline__ u32 pk_bf16(float a, float b) {
    float2 f; f.x = a; f.y = b;
    __hip_bfloat162 t = __float22bfloat162_rn(f);
    union { __hip_bfloat162 b2; u32 u; } v; v.b2 = t; return v.u;
}

__device__ __forceinline__ void llds16(const ushort_t* src, ushort_t* dst) {
    __builtin_amdgcn_global_load_lds((global_u32*)src, (lds_u32*)dst, 16, 0, 0);
}

// ------- fused weight transpose+convert: all 6 weights, one dispatch ---------
__global__ void transpose_w_all(
    const float* __restrict__ Wq, const float* __restrict__ Wk,
    const float* __restrict__ Wv, const float* __restrict__ Wo,
    const float* __restrict__ W1, const float* __restrict__ W2,
    ushort_t* __restrict__ Wqkv, ushort_t* __restrict__ Wo_t,
    ushort_t* __restrict__ W1_t, ushort_t* __restrict__ W2_t) {
    __shared__ float tile[64][65];
    int id = blockIdx.x;
    const float* W; ushort_t* Wt; int K, N, ntx, lid;
    if (id < 1024) {
        int which = id >> 8; lid = id & 255; K = 1024; N = 1024; ntx = 16;
        W  = which == 0 ? Wq : which == 1 ? Wk : which == 2 ? Wv : Wo;
        Wt = which == 3 ? Wo_t : Wqkv + (size_t)which * 1024 * 1024;
    } else if (id < 1536) {
        lid = id - 1024; W = W1; Wt = W1_t; K = 1024; N = 2048; ntx = 32;
    } else {
        lid = id - 1536; W = W2; Wt = W2_t; K = 2048; N = 1024; ntx = 16;
    }
    int n0 = (lid % ntx) * 64, k0 = (lid / ntx) * 64;
    int t = threadIdx.x;
    for (int p = 0; p < 4; ++p) {
        int k = p * 16 + (t >> 4), nn = (t & 15) * 4;
        float4 v = *(const float4*)(W + (size_t)(k0 + k) * N + n0 + nn);
        tile[k][nn] = v.x; tile[k][nn + 1] = v.y; tile[k][nn + 2] = v.z; tile[k][nn + 3] = v.w;
    }
    __syncthreads();
    for (int p = 0; p < 4; ++p) {
        int n = p * 16 + (t >> 4), kk = (t & 15) * 4;
        ushort4 o;
        o.x = f2bf(tile[kk][n]); o.y = f2bf(tile[kk + 1][n]);
        o.z = f2bf(tile[kk + 2][n]); o.w = f2bf(tile[kk + 3][n]);
        *(ushort4*)(Wt + (size_t)(n0 + n) * K + k0 + kk) = o;
    }
}

// ---------------- ada = silu(c) @ Wada + bada: split-k GEMV ------------------
__global__ void ada_gemv(const float* __restrict__ c, const float* __restrict__ Wada,
                         float* __restrict__ partial) {
    int ks = blockIdx.y;
    int j = blockIdx.x * 256 + threadIdx.x;
    __shared__ float s0[64], s1[64];
    if (threadIdx.x < 64) {
        float v = c[ks * 64 + threadIdx.x];
        s0[threadIdx.x] = v / (1.f + __expf(-v));
        v = c[D_ + ks * 64 + threadIdx.x];
        s1[threadIdx.x] = v / (1.f + __expf(-v));
    }
    __syncthreads();
    float a0 = 0.f, a1 = 0.f;
#pragma unroll 8
    for (int d = 0; d < 64; ++d) {
        float w = Wada[(size_t)(ks * 64 + d) * ADA_ + j];
        a0 = fmaf(s0[d], w, a0);
        a1 = fmaf(s1[d], w, a1);
    }
    partial[(size_t)(ks * 2 + 0) * ADA_ + j] = a0;
    partial[(size_t)(ks * 2 + 1) * ADA_ + j] = a1;
}

__global__ void ada_reduce(const float* __restrict__ partial,
                           const float* __restrict__ bada, float* __restrict__ ada) {
    int j = blockIdx.x * 256 + threadIdx.x;
    float a0 = bada[j], a1 = bada[j];
#pragma unroll
    for (int ks = 0; ks < 16; ++ks) {
        a0 += partial[(size_t)(ks * 2 + 0) * ADA_ + j];
        a1 += partial[(size_t)(ks * 2 + 1) * ADA_ + j];
    }
    ada[j] = a0;
    ada[ADA_ + j] = a1;
}

// ---------------- LayerNorm + modulation -> bf16 -----------------------------
__global__ void ln_mod(const float* __restrict__ x, const float* __restrict__ ada,
                       int so, int co, ushort_t* __restrict__ out) {
    int row = blockIdx.x;
    int b = row >> 11;
    float4 v = ((const float4*)(x + (size_t)row * D_))[threadIdx.x];
    float sum = v.x + v.y + v.z + v.w;
    float sq = v.x * v.x + v.y * v.y + v.z * v.z + v.w * v.w;
    for (int off = 32; off; off >>= 1) { sum += __shfl_down(sum, off); sq += __shfl_down(sq, off); }
    __shared__ float sa[4], sb[4];
    int wave = threadIdx.x >> 6, lane = threadIdx.x & 63;
    if (lane == 0) { sa[wave] = sum; sb[wave] = sq; }
    __syncthreads();
    sum = sa[0] + sa[1] + sa[2] + sa[3];
    sq = sb[0] + sb[1] + sb[2] + sb[3];
    float mean = sum * (1.f / 1024.f);
    float var = sq * (1.f / 1024.f) - mean * mean;
    float rstd = rsqrtf(var + 1e-6f);
    int d = threadIdx.x * 4;
    const float* shf = ada + (size_t)b * ADA_ + so;
    const float* scf = ada + (size_t)b * ADA_ + co;
    uint2 ov;
    ov.x = pk_bf16((v.x - mean) * rstd * (1.f + scf[d + 0]) + shf[d + 0],
                   (v.y - mean) * rstd * (1.f + scf[d + 1]) + shf[d + 1]);
    ov.y = pk_bf16((v.z - mean) * rstd * (1.f + scf[d + 2]) + shf[d + 2],
                   (v.w - mean) * rstd * (1.f + scf[d + 3]) + shf[d + 3]);
    *(uint2*)(out + (size_t)row * D_ + d) = ov;
}

// ---------------- GEMM epilogues ---------------------------------------------
struct EpiArgs {
    const float* bias0; const float* bias1; const float* bias2;
    ushort_t* o0; ushort_t* o1; ushort_t* o2;
    const float* resid; const float* gate;
    float* fout;
};

template <int EPI>
__device__ __forceinline__ void epi_store(float v, int m, int n, int N, const EpiArgs& e) {
    if (EPI == 0) {  // Q/K -> (B,H,L,DH) bf16; Q pre-scaled by log2(e)/8
        int which = n >> 10, cc = n & 1023;
        const float* bias = which == 0 ? e.bias0 : e.bias1;
        ushort_t* ob = which == 0 ? e.o0 : e.o1;
        v += bias[cc];
        if (which == 0) v *= 0.18033688f;  // (1/8) * log2(e): softmax uses exp2
        int b = m >> 11, l = m & 2047, h = cc >> 6, dh = cc & 63;
        ob[(((size_t)(b * H_ + h) * L_) + l) * DH_ + dh] = f2bf(v);
    } else if (EPI == 1) {  // bias + exact GELU -> bf16
        v += e.bias0[n];
        v = 0.5f * v * (1.f + erff(v * 0.70710678118f));
        e.o0[(size_t)m * N + n] = f2bf(v);
    } else {  // residual + gate -> fp32
        int b = m >> 11;
        e.fout[(size_t)m * N + n] =
            e.resid[(size_t)m * N + n] + e.gate[(size_t)b * ADA_ + n] * (v + e.bias0[n]);
    }
}

template <int EPI>
__device__ __forceinline__ void st4(const f32x4& cc, int mb, int n, int N, const EpiArgs& e) {
    if (EPI == 0 && n >= 2048) {
        // V: direct transpose write -> (BH, DH, L) bf16. mb..mb+3 are 4
        // consecutive l within one batch -> contiguous ushort4 in V^T.
        int ccn = n & 1023;
        float b4 = e.bias2[ccn];
        int b = mb >> 11, l0 = mb & 2047, h = ccn >> 6, dh = ccn & 63;
        ushort4 o;
        o.x = f2bf(cc[0] + b4); o.y = f2bf(cc[1] + b4);
        o.z = f2bf(cc[2] + b4); o.w = f2bf(cc[3] + b4);
        *(ushort4*)(e.o2 + ((size_t)(b * H_ + h) * DH_ + dh) * L_ + l0) = o;
        return;
    }
#pragma unroll
    for (int r = 0; r < 4; ++r) epi_store<EPI>(cc[r], mb + r, n, N, e);
}

// ---------------- GEMM 256x256 tile, 4-phase counted-vmcnt (QKV, MLP1) -------
// 8-phase-per-2-K-tiles structure (T3+T4 per m201/m218): 512 threads = 8
// waves (2M x 4N), per-wave output 128x64 (8x4 f32x4 acc). LDS 128 KB:
// A,B each 2 dbuf x 2 half-tiles of 128x64 bf16. Per K-tile, 4 phases of
// {ds_read frags | stage half-tiles of t+1 -> s_barrier -> lgkmcnt(0) ->
// setprio(1) 16xMFMA setprio(0) -> s_barrier}; staging issued in phases 0-1
// lands >=2 phases before the ONCE-per-tile vmcnt at tile end (loads span
// barriers; no per-phase drain -- the m218 mechanism the 2-barrier skeleton
// lacks). Requires gridDim.x % 8 == 0 and M == 4096.
template <int EPI>
__global__ __launch_bounds__(512, 2) void gemm256(
    const ushort_t* __restrict__ A, const ushort_t* __restrict__ Bt,
    int N, int K, EpiArgs e) {
    __shared__ ushort_t As[4 * 128 * 64];   // [buf*2+half][8192] ushort
    __shared__ ushort_t Bs[4 * 128 * 64];
    int nwg = gridDim.x, cpx = nwg >> 3;
    int wg = (blockIdx.x & 7) * cpx + (blockIdx.x >> 3);   // bijective: nwg%8==0
    int m0 = (wg & 15) * 256, n0 = (wg >> 4) * 256;
    int NT = K >> 6;
    int tid = threadIdx.x, wave = tid >> 6, lane = tid & 63;
    int wr = wave >> 2, wc = wave & 3;
    int quad = lane >> 4, lc = lane & 15, sw = lc & 7;
    int srow = lane >> 3, sg = lane & 7;

    // staging: each wave stages chunks {2w, 2w+1} of each 128x64 half-tile;
    // roles 0,1 = A half 0,1; roles 2,3 = B half 0,1
    const ushort_t* sp[4][2];
    int ldo[2];
#pragma unroll
    for (int i = 0; i < 2; ++i) {
        int c = wave * 2 + i, row8 = c * 8 + srow;
        sp[0][i] = A  + (size_t)(m0 +       row8) * K + (sg ^ srow) * 8;
        sp[1][i] = A  + (size_t)(m0 + 128 + row8) * K + (sg ^ srow) * 8;
        sp[2][i] = Bt + (size_t)(n0 +       row8) * K + (sg ^ srow) * 8;
        sp[3][i] = Bt + (size_t)(n0 + 128 + row8) * K + (sg ^ srow) * 8;
        ldo[i] = c * 512 + lane * 8;
    }

    // prologue: stage tile 0 (4 half-tiles) into buf 0
#pragma unroll
    for (int p = 0; p < 4; ++p)
#pragma unroll
        for (int i = 0; i < 2; ++i) {
            ushort_t* base = (p < 2 ? As : Bs) + (p & 1) * 8192;
            llds16(sp[p][i], base + ldo[i]);
            sp[p][i] += 64;
        }
    asm volatile("s_waitcnt vmcnt(0)" ::: "memory");
    __builtin_amdgcn_s_barrier();

    f32x4 acc[8][4] = {};

    for (int t = 0; t < NT; ++t) {
        int buf = t & 1, nb = buf ^ 1;
        bool haveNext = (t < NT - 1);
        const ushort_t* Ah = &As[(buf * 2 + wr) * 8192];
        const ushort_t* Bh = &Bs[(buf * 2 + (wc >> 1)) * 8192];
        int rb0 = (wc & 1) * 64;
        bf16x8 Bf[2][4];
#pragma unroll
        for (int p = 0; p < 4; ++p) {
            bf16x8 Af[2][2];
#pragma unroll
            for (int c = 0; c < 2; ++c) {
                int row = (2 * p + c) * 16 + lc;
#pragma unroll
                for (int kk = 0; kk < 2; ++kk)
                    Af[kk][c] = *(const bf16x8*)&Ah[row * 64 + (((kk * 4 + quad) ^ sw) * 8)];
            }
            if (p == 0) {
#pragma unroll
                for (int nf = 0; nf < 4; ++nf) {
                    int row = rb0 + nf * 16 + lc;
#pragma unroll
                    for (int kk = 0; kk < 2; ++kk)
                        Bf[kk][nf] = *(const bf16x8*)&Bh[row * 64 + (((kk * 4 + quad) ^ sw) * 8)];
                }
            }
            if (p < 2 && haveNext) {
                // phase 0: stage A halves of tile t+1; phase 1: B halves
#pragma unroll
                for (int h = 0; h < 2; ++h)
#pragma unroll
                    for (int i = 0; i < 2; ++i) {
                        int role = p * 2 + h;
                        ushort_t* base = (role < 2 ? As : Bs) + (nb * 2 + (role & 1)) * 8192;
                        llds16(sp[role][i], base + ldo[i]);
                        sp[role][i] += 64;
                    }
            }
            __builtin_amdgcn_s_barrier();
            asm volatile("s_waitcnt lgkmcnt(0)" ::: "memory");
            __builtin_amdgcn_s_setprio(1);
#pragma unroll
            for (int kk = 0; kk < 2; ++kk)
#pragma unroll
                for (int c = 0; c < 2; ++c)
#pragma unroll
                    for (int nf = 0; nf < 4; ++nf)
                        acc[2 * p + c][nf] = MFMA(Af[kk][c], Bf[kk][nf], acc[2 * p + c][nf], 0, 0, 0);
            __builtin_amdgcn_s_setprio(0);
            if (p < 3) __builtin_amdgcn_s_barrier();
        }
        if (haveNext) {
            // tile t+1's 8 loads/wave were issued in phases 0-1; by now >=2
            // phases of compute have covered their latency. Per-wave wait +
            // barrier makes the whole tile visible to all waves.
            asm volatile("s_waitcnt vmcnt(0)" ::: "memory");
            __builtin_amdgcn_s_barrier();
        }
    }

    // epilogue: rows mf*16 + quad*4 + r, cols nf*16 + lc (C layout)
    int mb = m0 + wr * 128 + quad * 4;
    int nb2 = n0 + wc * 64 + lc;
#pragma unroll
    for (int mf = 0; mf < 8; ++mf)
#pragma unroll
        for (int nf = 0; nf < 4; ++nf)
            st4<EPI>(acc[mf][nf], mb + mf * 16, nb2 + nf * 16, N, e);
}

// ---------------- GEMM 64x128 tile, BK=64 (O-proj, MLP2: N=1024) -------------
template <int EPI>
__global__ __launch_bounds__(256, 2) void gemm_bt64(
    const ushort_t* __restrict__ A, const ushort_t* __restrict__ Bt,
    int M, int N, int K, EpiArgs e) {
    __shared__ ushort_t As[64 * 64];    // 8 KB
    __shared__ ushort_t Bs[128 * 64];   // 16 KB
    int m0 = blockIdx.x * 64, n0 = blockIdx.y * 128;
    int tid = threadIdx.x, wave = tid >> 6, lane = tid & 63;
    int quad = lane >> 4, lc = lane & 15;
    int wn = wave * 32;
    int srow = lane >> 3, sg = lane & 7;
    int sw = lc & 7;

    const ushort_t* stp[6];
    ushort_t* stl[6];
#pragma unroll
    for (int i = 0; i < 6; ++i) {
        int chunk = wave * 6 + i;
        if (chunk < 8) {
            int row = chunk * 8 + srow;
            stp[i] = A + (size_t)(m0 + row) * K + (sg ^ srow) * 8;
            stl[i] = &As[chunk * 512 + lane * 8];
        } else {
            int c = chunk - 8;
            int row = c * 8 + srow;
            stp[i] = Bt + (size_t)(n0 + row) * K + (sg ^ srow) * 8;
            stl[i] = &Bs[c * 512 + lane * 8];
        }
    }

    f32x4 c00 = {}, c01 = {};
    f32x4 c10 = {}, c11 = {};
    f32x4 c20 = {}, c21 = {};
    f32x4 c30 = {}, c31 = {};

    for (int k0 = 0; k0 < K; k0 += 64) {
#pragma unroll
        for (int i = 0; i < 6; ++i) { llds16(stp[i], stl[i]); stp[i] += 64; }
        __syncthreads();
#pragma unroll
        for (int kk = 0; kk < 2; ++kk) {
            int off = ((kk * 4 + quad) ^ sw) * 8;
            bf16x8 a0 = *(const bf16x8*)&As[( 0 + lc) * 64 + off];
            bf16x8 a1 = *(const bf16x8*)&As[(16 + lc) * 64 + off];
            bf16x8 a2 = *(const bf16x8*)&As[(32 + lc) * 64 + off];
            bf16x8 a3 = *(const bf16x8*)&As[(48 + lc) * 64 + off];
            bf16x8 b0 = *(const bf16x8*)&Bs[(wn +  0 + lc) * 64 + off];
            bf16x8 b1 = *(const bf16x8*)&Bs[(wn + 16 + lc) * 64 + off];
            c00 = MFMA(a0, b0, c00, 0, 0, 0); c01 = MFMA(a0, b1, c01, 0, 0, 0);
            c10 = MFMA(a1, b0, c10, 0, 0, 0); c11 = MFMA(a1, b1, c11, 0, 0, 0);
            c20 = MFMA(a2, b0, c20, 0, 0, 0); c21 = MFMA(a2, b1, c21, 0, 0, 0);
            c30 = MFMA(a3, b0, c30, 0, 0, 0); c31 = MFMA(a3, b1, c31, 0, 0, 0);
        }
        __syncthreads();
    }

    int mb = m0 + quad * 4, nb = n0 + wn + lc;
    st4<EPI>(c00, mb +  0, nb + 0, N, e); st4<EPI>(c01, mb +  0, nb + 16, N, e);
    st4<EPI>(c10, mb + 16, nb + 0, N, e); st4<EPI>(c11, mb + 16, nb + 16, N, e);
    st4<EPI>(c20, mb + 32, nb + 0, N, e); st4<EPI>(c21, mb + 32, nb + 16, N, e);
    st4<EPI>(c30, mb + 48, nb + 0, N, e); st4<EPI>(c31, mb + 48, nb + 16, N, e);
}

// ---------------- flash attention v14 (best measured): 8-wave, single buf ----
__global__ __launch_bounds__(512, 4) void attn(
    const ushort_t* __restrict__ Q, const ushort_t* __restrict__ Kx,
    const ushort_t* __restrict__ Vt, ushort_t* __restrict__ O) {
    __shared__ ushort_t Ks[128 * 64];     // 16 KB
    __shared__ ushort_t Vs[64 * 128];     // 16 KB
    int id = blockIdx.x;
    int bh = ((id & 7) << 2) + ((id >> 3) & 3);  // 4 bh per XCD class
    int qt = id >> 5;                            // 16 q-tiles of 128 rows
    const ushort_t* Qg = Q + ((size_t)bh * L_ + qt * 128) * DH_;
    const ushort_t* Kg = Kx + (size_t)bh * L_ * DH_;
    const ushort_t* Vg = Vt + (size_t)bh * DH_ * L_;
    int tid = threadIdx.x, wave = tid >> 6, lane = tid & 63;
    int quad = lane >> 4, lc = lane & 15;
    int sw = lc & 7;
    int srow = lane >> 3, sg = lane & 7;

    const ushort_t* stp[4];
    ushort_t* stl[4];
    int stinc;
    if (wave < 4) {
        stinc = 128 * DH_;
#pragma unroll
        for (int i = 0; i < 4; ++i) {
            int chunk = wave * 4 + i;            // 0..15
            int slot = chunk * 8 + srow;         // LDS row (slot)
            int s5 = slot & 31;                  // within-32 position
            int sig = (slot & ~31) + ((s5 & 15) >> 2) * 8 + (s5 & 3) + (s5 >> 4) * 4;
            stp[i] = Kg + (size_t)sig * DH_ + (sg ^ srow) * 8;
            stl[i] = &Ks[chunk * 512 + lane * 8];
        }
    } else {
        stinc = 128;
#pragma unroll
        for (int i = 0; i < 4; ++i) {
            int c2 = (wave - 4) * 4 + i;         // 0..15
            int row = c2 * 4 + (lane >> 4);
            int g = (lane & 15) ^ (row & 15);
            stp[i] = Vg + (size_t)row * L_ + g * 8;
            stl[i] = &Vs[c2 * 512 + lane * 8];
        }
    }

    const ushort_t* qp = Qg + (size_t)(wave * 16 + lc) * DH_ + quad * 8;
    bf16x8 q0 = *(const bf16x8*)(qp);        // kk0: dh 0..31 (quad-sliced)
    bf16x8 q1 = *(const bf16x8*)(qp + 32);   // kk1: dh 32..63

    union { u32 u[4]; bf16x8 v; } ones;
    ones.u[0] = ones.u[1] = ones.u[2] = ones.u[3] = 0x3F803F80u;

    f32x4 o0 = {}, o1 = {}, o2 = {}, o3 = {};
    f32x4 osum = {};   // rowsum accumulator (cols redundant)

    for (int t = 0; t < 16; ++t) {
#pragma unroll
        for (int i = 0; i < 4; ++i) { llds16(stp[i], stl[i]); stp[i] += stinc; }
        __syncthreads();

        f32x4 s[8];
        __builtin_amdgcn_s_setprio(1);
#pragma unroll
        for (int kk = 0; kk < 2; ++kk) {
            int off = ((kk * 4 + quad) ^ sw) * 8;
            bf16x8 aq = kk == 0 ? q0 : q1;
#pragma unroll
            for (int ni = 0; ni < 8; ++ni) {
                bf16x8 bk = *(const bf16x8*)&Ks[(ni * 16 + lc) * 64 + off];
                if (kk == 0) {
                    f32x4 z = {0.f, 0.f, 0.f, 0.f};
                    s[ni] = MFMA(bk, aq, z, 0, 0, 0);
                } else {
                    s[ni] = MFMA(bk, aq, s[ni], 0, 0, 0);
                }
            }
        }
        __builtin_amdgcn_s_setprio(0);

        u32 px[8], py[8];
#pragma unroll
        for (int ni = 0; ni < 8; ++ni) {
            float p0 = __builtin_amdgcn_exp2f(s[ni][0]);
            float p1 = __builtin_amdgcn_exp2f(s[ni][1]);
            float p2 = __builtin_amdgcn_exp2f(s[ni][2]);
            float p3 = __builtin_amdgcn_exp2f(s[ni][3]);
            px[ni] = pk_bf16(p0, p1);
            py[ni] = pk_bf16(p2, p3);
        }

        __builtin_amdgcn_s_setprio(1);
#pragma unroll
        for (int kk = 0; kk < 4; ++kk) {
            int gq = kk * 4 + quad;
            bf16x8 bv0 = *(const bf16x8*)&Vs[( 0 + lc) * 128 + ((gq ^ lc) * 8)];
            bf16x8 bv1 = *(const bf16x8*)&Vs[(16 + lc) * 128 + ((gq ^ lc) * 8)];
            bf16x8 bv2 = *(const bf16x8*)&Vs[(32 + lc) * 128 + ((gq ^ lc) * 8)];
            bf16x8 bv3 = *(const bf16x8*)&Vs[(48 + lc) * 128 + ((gq ^ lc) * 8)];
            union { u32 u[4]; bf16x8 v; } a;
            a.u[0] = px[2 * kk]; a.u[1] = py[2 * kk];
            a.u[2] = px[2 * kk + 1]; a.u[3] = py[2 * kk + 1];
            o0 = MFMA(a.v, bv0, o0, 0, 0, 0); o1 = MFMA(a.v, bv1, o1, 0, 0, 0);
            o2 = MFMA(a.v, bv2, o2, 0, 0, 0); o3 = MFMA(a.v, bv3, o3, 0, 0, 0);
            osum = MFMA(a.v, ones.v, osum, 0, 0, 0);
        }
        __builtin_amdgcn_s_setprio(0);
        __syncthreads();  // Ks/Vs consumed before next tile's staging
    }

    f32x4 inv;
#pragma unroll
    for (int r = 0; r < 4; ++r) inv[r] = 1.f / osum[r];
#pragma unroll
    for (int nio = 0; nio < 4; ++nio) {
        const f32x4& ov = nio == 0 ? o0 : nio == 1 ? o1 : nio == 2 ? o2 : o3;
#pragma unroll
        for (int r = 0; r < 4; ++r) {
            int row = qt * 128 + wave * 16 + quad * 4 + r;
            O[((size_t)bh * L_ + row) * DH_ + nio * 16 + lc] = f2bf(ov[r] * inv[r]);
        }
    }
}

// -----------------------------------------------------------------------------
extern "C" void kernel_launch(void* const* d_in, const int* in_sizes, int n_in,
                              void* d_out, int out_size, void* d_ws, size_t ws_size,
                              hipStream_t stream) {
    (void)in_sizes; (void)n_in; (void)out_size; (void)ws_size;
    const float* x    = (const float*)d_in[0];
    const float* c    = (const float*)d_in[1];
    const float* Wq   = (const float*)d_in[2];
    const float* bq   = (const float*)d_in[3];
    const float* Wk   = (const float*)d_in[4];
    const float* bk   = (const float*)d_in[5];
    const float* Wv   = (const float*)d_in[6];
    const float* bv   = (const float*)d_in[7];
    const float* Wo   = (const float*)d_in[8];
    const float* bo   = (const float*)d_in[9];
    const float* W1   = (const float*)d_in[10];
    const float* b1   = (const float*)d_in[11];
    const float* W2   = (const float*)d_in[12];
    const float* b2   = (const float*)d_in[13];
    const float* Wada = (const float*)d_in[14];
    const float* bada = (const float*)d_in[15];

    char* w = (char*)d_ws;
    float*    ada  = (float*)(w + 0);                     // 49152 B
    ushort_t* Wqkv = (ushort_t*)(w + 49152);              // 6 MiB
    ushort_t* Wo_t = (ushort_t*)(w + 6340608);            // 2 MiB
    ushort_t* W1_t = (ushort_t*)(w + 8437760);            // 4 MiB
    ushort_t* W2_t = (ushort_t*)(w + 12632064);           // 4 MiB
    ushort_t* h    = (ushort_t*)(w + 16826368);           // 8 MiB (h / h2)
    ushort_t* Qb   = (ushort_t*)(w + 25214976);           // 8 MiB (Q)
    ushort_t* Kb   = (ushort_t*)(w + 33603584);           // 8 MiB (K)
    ushort_t* Ob   = (ushort_t*)(w + 41992192);           // 8 MiB (final O)
    ushort_t* Vtb  = (ushort_t*)(w + 50380800);           // 8 MiB (ada partials, then V^T)
    float*    x1   = (float*)(w + 58769408);              // 16 MiB (x1)
    ushort_t* m1   = Qb;            // MLP hidden (16 MiB = Qb+Kb, dead post-attn)
    float*    adap = (float*)Vtb;   // 786 KB split-k partials; dead before QKV gemm

    const int M = B_ * L_;  // 4096

    transpose_w_all<<<2048, 256, 0, stream>>>(Wq, Wk, Wv, Wo, W1, W2,
                                              Wqkv, Wo_t, W1_t, W2_t);

    ada_gemv<<<dim3(24, 16), 256, 0, stream>>>(c, Wada, adap);
    ada_reduce<<<24, 256, 0, stream>>>(adap, bada, ada);
    ln_mod<<<M, 256, 0, stream>>>(x, ada, 0, 1024, h);

    // QKV (M=4096, N=3072, K=1024): 256^2 8-phase kernel, 192 blocks
    EpiArgs e0 = {bq, bk, bv, Qb, Kb, Vtb, nullptr, nullptr, nullptr};
    gemm256<0><<<192, 512, 0, stream>>>(h, Wqkv, 3072, D_, e0);

    // full-KV attention: final O, no partials, no merge; 8-wave blocks
    attn<<<512, 512, 0, stream>>>(Qb, Kb, Vtb, Ob);

    EpiArgs e1 = {bo, nullptr, nullptr, nullptr, nullptr, nullptr, x, ada + 2048, x1};
    gemm_bt64<2><<<dim3(64, 8), 256, 0, stream>>>(Ob, Wo_t, M, D_, D_, e1);

    ln_mod<<<M, 256, 0, stream>>>(x1, ada, 3072, 4096, h);

    // MLP1 (M=4096, N=2048, K=1024): 256^2 8-phase kernel, 128 blocks
    EpiArgs e2 = {b1, nullptr, nullptr, m1, nullptr, nullptr, nullptr, nullptr, nullptr};
    gemm256<1><<<128, 512, 0, stream>>>(h, W1_t, FF_, D_, e2);

    EpiArgs e3 = {b2, nullptr, nullptr, nullptr, nullptr, nullptr, x1, ada + 5120, (float*)d_out};
    gemm_bt64<2><<<dim3(64, 8), 256, 0, stream>>>(m1, W2_t, M, D_, FF_, e3);
}

// Round 10
// 317.035 us; speedup vs baseline: 1.0641x; 1.0641x over previous
//
#include <hip/hip_runtime.h>
#include <hip/hip_bf16.h>

typedef unsigned short ushort_t;
typedef __bf16 bf16x8 __attribute__((ext_vector_type(8)));
typedef float f32x4 __attribute__((ext_vector_type(4)));

typedef unsigned int u32;
typedef u32 __attribute__((address_space(1))) global_u32;
typedef u32 __attribute__((address_space(3))) lds_u32;

#define D_ 1024
#define L_ 2048
#define B_ 2
#define H_ 16
#define DH_ 64
#define FF_ 2048
#define ADA_ 6144
#define BHL_ (B_ * H_ * L_)

#define MFMA __builtin_amdgcn_mfma_f32_16x16x32_bf16

__device__ __forceinline__ ushort_t f2bf(float f) {
    union { float f; u32 u; } v; v.f = f;
    u32 r = v.u + 0x7fffu + ((v.u >> 16) & 1u);
    return (ushort_t)(r >> 16);
}

// packed 2xf32 -> 2xbf16 (v_cvt_pk_bf16_f32)
__device__ __forceinline__ u32 pk_bf16(float a, float b) {
    float2 f; f.x = a; f.y = b;
    __hip_bfloat162 t = __float22bfloat162_rn(f);
    union { __hip_bfloat162 b2; u32 u; } v; v.b2 = t; return v.u;
}

__device__ __forceinline__ void llds16(const ushort_t* src, ushort_t* dst) {
    __builtin_amdgcn_global_load_lds((global_u32*)src, (lds_u32*)dst, 16, 0, 0);
}

// ------- fused weight transpose+convert: all 6 weights, one dispatch ---------
__global__ void transpose_w_all(
    const float* __restrict__ Wq, const float* __restrict__ Wk,
    const float* __restrict__ Wv, const float* __restrict__ Wo,
    const float* __restrict__ W1, const float* __restrict__ W2,
    ushort_t* __restrict__ Wqkv, ushort_t* __restrict__ Wo_t,
    ushort_t* __restrict__ W1_t, ushort_t* __restrict__ W2_t) {
    __shared__ float tile[64][65];
    int id = blockIdx.x;
    const float* W; ushort_t* Wt; int K, N, ntx, lid;
    if (id < 1024) {
        int which = id >> 8; lid = id & 255; K = 1024; N = 1024; ntx = 16;
        W  = which == 0 ? Wq : which == 1 ? Wk : which == 2 ? Wv : Wo;
        Wt = which == 3 ? Wo_t : Wqkv + (size_t)which * 1024 * 1024;
    } else if (id < 1536) {
        lid = id - 1024; W = W1; Wt = W1_t; K = 1024; N = 2048; ntx = 32;
    } else {
        lid = id - 1536; W = W2; Wt = W2_t; K = 2048; N = 1024; ntx = 16;
    }
    int n0 = (lid % ntx) * 64, k0 = (lid / ntx) * 64;
    int t = threadIdx.x;
    for (int p = 0; p < 4; ++p) {
        int k = p * 16 + (t >> 4), nn = (t & 15) * 4;
        float4 v = *(const float4*)(W + (size_t)(k0 + k) * N + n0 + nn);
        tile[k][nn] = v.x; tile[k][nn + 1] = v.y; tile[k][nn + 2] = v.z; tile[k][nn + 3] = v.w;
    }
    __syncthreads();
    for (int p = 0; p < 4; ++p) {
        int n = p * 16 + (t >> 4), kk = (t & 15) * 4;
        ushort4 o;
        o.x = f2bf(tile[kk][n]); o.y = f2bf(tile[kk + 1][n]);
        o.z = f2bf(tile[kk + 2][n]); o.w = f2bf(tile[kk + 3][n]);
        *(ushort4*)(Wt + (size_t)(n0 + n) * K + k0 + kk) = o;
    }
}

// ---------------- ada = silu(c) @ Wada + bada: split-k GEMV ------------------
__global__ void ada_gemv(const float* __restrict__ c, const float* __restrict__ Wada,
                         float* __restrict__ partial) {
    int ks = blockIdx.y;
    int j = blockIdx.x * 256 + threadIdx.x;
    __shared__ float s0[64], s1[64];
    if (threadIdx.x < 64) {
        float v = c[ks * 64 + threadIdx.x];
        s0[threadIdx.x] = v / (1.f + __expf(-v));
        v = c[D_ + ks * 64 + threadIdx.x];
        s1[threadIdx.x] = v / (1.f + __expf(-v));
    }
    __syncthreads();
    float a0 = 0.f, a1 = 0.f;
#pragma unroll 8
    for (int d = 0; d < 64; ++d) {
        float w = Wada[(size_t)(ks * 64 + d) * ADA_ + j];
        a0 = fmaf(s0[d], w, a0);
        a1 = fmaf(s1[d], w, a1);
    }
    partial[(size_t)(ks * 2 + 0) * ADA_ + j] = a0;
    partial[(size_t)(ks * 2 + 1) * ADA_ + j] = a1;
}

__global__ void ada_reduce(const float* __restrict__ partial,
                           const float* __restrict__ bada, float* __restrict__ ada) {
    int j = blockIdx.x * 256 + threadIdx.x;
    float a0 = bada[j], a1 = bada[j];
#pragma unroll
    for (int ks = 0; ks < 16; ++ks) {
        a0 += partial[(size_t)(ks * 2 + 0) * ADA_ + j];
        a1 += partial[(size_t)(ks * 2 + 1) * ADA_ + j];
    }
    ada[j] = a0;
    ada[ADA_ + j] = a1;
}

// ---------------- LayerNorm + modulation -> bf16 -----------------------------
__global__ void ln_mod(const float* __restrict__ x, const float* __restrict__ ada,
                       int so, int co, ushort_t* __restrict__ out) {
    int row = blockIdx.x;
    int b = row >> 11;
    float4 v = ((const float4*)(x + (size_t)row * D_))[threadIdx.x];
    float sum = v.x + v.y + v.z + v.w;
    float sq = v.x * v.x + v.y * v.y + v.z * v.z + v.w * v.w;
    for (int off = 32; off; off >>= 1) { sum += __shfl_down(sum, off); sq += __shfl_down(sq, off); }
    __shared__ float sa[4], sb[4];
    int wave = threadIdx.x >> 6, lane = threadIdx.x & 63;
    if (lane == 0) { sa[wave] = sum; sb[wave] = sq; }
    __syncthreads();
    sum = sa[0] + sa[1] + sa[2] + sa[3];
    sq = sb[0] + sb[1] + sb[2] + sb[3];
    float mean = sum * (1.f / 1024.f);
    float var = sq * (1.f / 1024.f) - mean * mean;
    float rstd = rsqrtf(var + 1e-6f);
    int d = threadIdx.x * 4;
    const float* shf = ada + (size_t)b * ADA_ + so;
    const float* scf = ada + (size_t)b * ADA_ + co;
    uint2 ov;
    ov.x = pk_bf16((v.x - mean) * rstd * (1.f + scf[d + 0]) + shf[d + 0],
                   (v.y - mean) * rstd * (1.f + scf[d + 1]) + shf[d + 1]);
    ov.y = pk_bf16((v.z - mean) * rstd * (1.f + scf[d + 2]) + shf[d + 2],
                   (v.w - mean) * rstd * (1.f + scf[d + 3]) + shf[d + 3]);
    *(uint2*)(out + (size_t)row * D_ + d) = ov;
}

// ---------------- GEMM epilogues ---------------------------------------------
struct EpiArgs {
    const float* bias0; const float* bias1; const float* bias2;
    ushort_t* o0; ushort_t* o1; ushort_t* o2;
    const float* resid; const float* gate;
    float* fout;
};

template <int EPI>
__device__ __forceinline__ void epi_store(float v, int m, int n, int N, const EpiArgs& e) {
    if (EPI == 0) {  // Q/K -> (B,H,L,DH) bf16; Q pre-scaled by log2(e)/8
        int which = n >> 10, cc = n & 1023;
        const float* bias = which == 0 ? e.bias0 : e.bias1;
        ushort_t* ob = which == 0 ? e.o0 : e.o1;
        v += bias[cc];
        if (which == 0) v *= 0.18033688f;  // (1/8) * log2(e): softmax uses exp2
        int b = m >> 11, l = m & 2047, h = cc >> 6, dh = cc & 63;
        ob[(((size_t)(b * H_ + h) * L_) + l) * DH_ + dh] = f2bf(v);
    } else if (EPI == 1) {  // bias + exact GELU -> bf16
        v += e.bias0[n];
        v = 0.5f * v * (1.f + erff(v * 0.70710678118f));
        e.o0[(size_t)m * N + n] = f2bf(v);
    } else {  // residual + gate -> fp32
        int b = m >> 11;
        e.fout[(size_t)m * N + n] =
            e.resid[(size_t)m * N + n] + e.gate[(size_t)b * ADA_ + n] * (v + e.bias0[n]);
    }
}

template <int EPI>
__device__ __forceinline__ void st4(const f32x4& cc, int mb, int n, int N, const EpiArgs& e) {
    if (EPI == 0 && n >= 2048) {
        // V: direct transpose write -> (BH, DH, L) bf16. mb..mb+3 are 4
        // consecutive l within one batch -> contiguous ushort4 in V^T.
        int ccn = n & 1023;
        float b4 = e.bias2[ccn];
        int b = mb >> 11, l0 = mb & 2047, h = ccn >> 6, dh = ccn & 63;
        ushort4 o;
        o.x = f2bf(cc[0] + b4); o.y = f2bf(cc[1] + b4);
        o.z = f2bf(cc[2] + b4); o.w = f2bf(cc[3] + b4);
        *(ushort4*)(e.o2 + ((size_t)(b * H_ + h) * DH_ + dh) * L_ + l0) = o;
        return;
    }
#pragma unroll
    for (int r = 0; r < 4; ++r) epi_store<EPI>(cc[r], mb + r, n, N, e);
}

// ---------------- GEMM 128x128 tile (QKV, MLP1) ------------------------------
template <int EPI>
__global__ __launch_bounds__(256, 2) void gemm_bt(
    const ushort_t* __restrict__ A, const ushort_t* __restrict__ Bt,
    int M, int N, int K, EpiArgs e) {
    __shared__ ushort_t As[128 * 64];
    __shared__ ushort_t Bs[128 * 64];
    int m0 = blockIdx.x * 128, n0 = blockIdx.y * 128;
    int tid = threadIdx.x, wave = tid >> 6, lane = tid & 63;
    int quad = lane >> 4, lc = lane & 15;
    int wm = (wave & 1) * 64, wn = (wave >> 1) * 64;
    int srow = lane >> 3, sg = lane & 7;
    int sw = lc & 7;

    const ushort_t* stp[8];
    ushort_t* stl[8];
#pragma unroll
    for (int i = 0; i < 8; ++i) {
        int chunk = wave * 8 + i;
        int c = chunk & 15;
        int row = c * 8 + srow;
        stp[i] = (chunk < 16 ? A + (size_t)(m0 + row) * K
                             : Bt + (size_t)(n0 + row) * K) + (sg ^ srow) * 8;
        stl[i] = (chunk < 16 ? As : Bs) + c * 512 + lane * 8;
    }

    f32x4 c00 = {}, c01 = {}, c02 = {}, c03 = {};
    f32x4 c10 = {}, c11 = {}, c12 = {}, c13 = {};
    f32x4 c20 = {}, c21 = {}, c22 = {}, c23 = {};
    f32x4 c30 = {}, c31 = {}, c32 = {}, c33 = {};

    for (int k0 = 0; k0 < K; k0 += 64) {
#pragma unroll
        for (int i = 0; i < 8; ++i) { llds16(stp[i], stl[i]); stp[i] += 64; }
        __syncthreads();
#pragma unroll
        for (int kk = 0; kk < 2; ++kk) {
            int off = ((kk * 4 + quad) ^ sw) * 8;
            bf16x8 a0 = *(const bf16x8*)&As[(wm +  0 + lc) * 64 + off];
            bf16x8 a1 = *(const bf16x8*)&As[(wm + 16 + lc) * 64 + off];
            bf16x8 a2 = *(const bf16x8*)&As[(wm + 32 + lc) * 64 + off];
            bf16x8 a3 = *(const bf16x8*)&As[(wm + 48 + lc) * 64 + off];
            bf16x8 b0 = *(const bf16x8*)&Bs[(wn +  0 + lc) * 64 + off];
            bf16x8 b1 = *(const bf16x8*)&Bs[(wn + 16 + lc) * 64 + off];
            bf16x8 b2 = *(const bf16x8*)&Bs[(wn + 32 + lc) * 64 + off];
            bf16x8 b3 = *(const bf16x8*)&Bs[(wn + 48 + lc) * 64 + off];
            c00 = MFMA(a0, b0, c00, 0, 0, 0); c01 = MFMA(a0, b1, c01, 0, 0, 0);
            c02 = MFMA(a0, b2, c02, 0, 0, 0); c03 = MFMA(a0, b3, c03, 0, 0, 0);
            c10 = MFMA(a1, b0, c10, 0, 0, 0); c11 = MFMA(a1, b1, c11, 0, 0, 0);
            c12 = MFMA(a1, b2, c12, 0, 0, 0); c13 = MFMA(a1, b3, c13, 0, 0, 0);
            c20 = MFMA(a2, b0, c20, 0, 0, 0); c21 = MFMA(a2, b1, c21, 0, 0, 0);
            c22 = MFMA(a2, b2, c22, 0, 0, 0); c23 = MFMA(a2, b3, c23, 0, 0, 0);
            c30 = MFMA(a3, b0, c30, 0, 0, 0); c31 = MFMA(a3, b1, c31, 0, 0, 0);
            c32 = MFMA(a3, b2, c32, 0, 0, 0); c33 = MFMA(a3, b3, c33, 0, 0, 0);
        }
        __syncthreads();
    }

    int mb = m0 + wm + quad * 4, nb = n0 + wn + lc;
    st4<EPI>(c00, mb +  0, nb +  0, N, e); st4<EPI>(c01, mb +  0, nb + 16, N, e);
    st4<EPI>(c02, mb +  0, nb + 32, N, e); st4<EPI>(c03, mb +  0, nb + 48, N, e);
    st4<EPI>(c10, mb + 16, nb +  0, N, e); st4<EPI>(c11, mb + 16, nb + 16, N, e);
    st4<EPI>(c12, mb + 16, nb + 32, N, e); st4<EPI>(c13, mb + 16, nb + 48, N, e);
    st4<EPI>(c20, mb + 32, nb +  0, N, e); st4<EPI>(c21, mb + 32, nb + 16, N, e);
    st4<EPI>(c22, mb + 32, nb + 32, N, e); st4<EPI>(c23, mb + 32, nb + 48, N, e);
    st4<EPI>(c30, mb + 48, nb +  0, N, e); st4<EPI>(c31, mb + 48, nb + 16, N, e);
    st4<EPI>(c32, mb + 48, nb + 32, N, e); st4<EPI>(c33, mb + 48, nb + 48, N, e);
}

// ---------------- GEMM 64x128 tile: N=1024 GEMMs need more blocks ------------
template <int EPI>
__global__ __launch_bounds__(256, 2) void gemm_bt64(
    const ushort_t* __restrict__ A, const ushort_t* __restrict__ Bt,
    int M, int N, int K, EpiArgs e) {
    __shared__ ushort_t As[64 * 64];    // 8 KB
    __shared__ ushort_t Bs[128 * 64];   // 16 KB
    int m0 = blockIdx.x * 64, n0 = blockIdx.y * 128;
    int tid = threadIdx.x, wave = tid >> 6, lane = tid & 63;
    int quad = lane >> 4, lc = lane & 15;
    int wn = wave * 32;
    int srow = lane >> 3, sg = lane & 7;
    int sw = lc & 7;

    const ushort_t* stp[6];
    ushort_t* stl[6];
#pragma unroll
    for (int i = 0; i < 6; ++i) {
        int chunk = wave * 6 + i;
        if (chunk < 8) {
            int row = chunk * 8 + srow;
            stp[i] = A + (size_t)(m0 + row) * K + (sg ^ srow) * 8;
            stl[i] = &As[chunk * 512 + lane * 8];
        } else {
            int c = chunk - 8;
            int row = c * 8 + srow;
            stp[i] = Bt + (size_t)(n0 + row) * K + (sg ^ srow) * 8;
            stl[i] = &Bs[c * 512 + lane * 8];
        }
    }

    f32x4 c00 = {}, c01 = {};
    f32x4 c10 = {}, c11 = {};
    f32x4 c20 = {}, c21 = {};
    f32x4 c30 = {}, c31 = {};

    for (int k0 = 0; k0 < K; k0 += 64) {
#pragma unroll
        for (int i = 0; i < 6; ++i) { llds16(stp[i], stl[i]); stp[i] += 64; }
        __syncthreads();
#pragma unroll
        for (int kk = 0; kk < 2; ++kk) {
            int off = ((kk * 4 + quad) ^ sw) * 8;
            bf16x8 a0 = *(const bf16x8*)&As[( 0 + lc) * 64 + off];
            bf16x8 a1 = *(const bf16x8*)&As[(16 + lc) * 64 + off];
            bf16x8 a2 = *(const bf16x8*)&As[(32 + lc) * 64 + off];
            bf16x8 a3 = *(const bf16x8*)&As[(48 + lc) * 64 + off];
            bf16x8 b0 = *(const bf16x8*)&Bs[(wn +  0 + lc) * 64 + off];
            bf16x8 b1 = *(const bf16x8*)&Bs[(wn + 16 + lc) * 64 + off];
            c00 = MFMA(a0, b0, c00, 0, 0, 0); c01 = MFMA(a0, b1, c01, 0, 0, 0);
            c10 = MFMA(a1, b0, c10, 0, 0, 0); c11 = MFMA(a1, b1, c11, 0, 0, 0);
            c20 = MFMA(a2, b0, c20, 0, 0, 0); c21 = MFMA(a2, b1, c21, 0, 0, 0);
            c30 = MFMA(a3, b0, c30, 0, 0, 0); c31 = MFMA(a3, b1, c31, 0, 0, 0);
        }
        __syncthreads();
    }

    int mb = m0 + quad * 4, nb = n0 + wn + lc;
    st4<EPI>(c00, mb +  0, nb + 0, N, e); st4<EPI>(c01, mb +  0, nb + 16, N, e);
    st4<EPI>(c10, mb + 16, nb + 0, N, e); st4<EPI>(c11, mb + 16, nb + 16, N, e);
    st4<EPI>(c20, mb + 32, nb + 0, N, e); st4<EPI>(c21, mb + 32, nb + 16, N, e);
    st4<EPI>(c30, mb + 48, nb + 0, N, e); st4<EPI>(c31, mb + 48, nb + 16, N, e);
}

// ---------------- flash attention v14 (best measured): 8-wave, single buf ----
__global__ __launch_bounds__(512, 4) void attn(
    const ushort_t* __restrict__ Q, const ushort_t* __restrict__ Kx,
    const ushort_t* __restrict__ Vt, ushort_t* __restrict__ O) {
    __shared__ ushort_t Ks[128 * 64];     // 16 KB
    __shared__ ushort_t Vs[64 * 128];     // 16 KB
    int id = blockIdx.x;
    int bh = ((id & 7) << 2) + ((id >> 3) & 3);  // 4 bh per XCD class
    int qt = id >> 5;                            // 16 q-tiles of 128 rows
    const ushort_t* Qg = Q + ((size_t)bh * L_ + qt * 128) * DH_;
    const ushort_t* Kg = Kx + (size_t)bh * L_ * DH_;
    const ushort_t* Vg = Vt + (size_t)bh * DH_ * L_;
    int tid = threadIdx.x, wave = tid >> 6, lane = tid & 63;
    int quad = lane >> 4, lc = lane & 15;
    int sw = lc & 7;
    int srow = lane >> 3, sg = lane & 7;

    const ushort_t* stp[4];
    ushort_t* stl[4];
    int stinc;
    if (wave < 4) {
        stinc = 128 * DH_;
#pragma unroll
        for (int i = 0; i < 4; ++i) {
            int chunk = wave * 4 + i;            // 0..15
            int slot = chunk * 8 + srow;         // LDS row (slot)
            int s5 = slot & 31;                  // within-32 position
            int sig = (slot & ~31) + ((s5 & 15) >> 2) * 8 + (s5 & 3) + (s5 >> 4) * 4;
            stp[i] = Kg + (size_t)sig * DH_ + (sg ^ srow) * 8;
            stl[i] = &Ks[chunk * 512 + lane * 8];
        }
    } else {
        stinc = 128;
#pragma unroll
        for (int i = 0; i < 4; ++i) {
            int c2 = (wave - 4) * 4 + i;         // 0..15
            int row = c2 * 4 + (lane >> 4);
            int g = (lane & 15) ^ (row & 15);
            stp[i] = Vg + (size_t)row * L_ + g * 8;
            stl[i] = &Vs[c2 * 512 + lane * 8];
        }
    }

    const ushort_t* qp = Qg + (size_t)(wave * 16 + lc) * DH_ + quad * 8;
    bf16x8 q0 = *(const bf16x8*)(qp);        // kk0: dh 0..31 (quad-sliced)
    bf16x8 q1 = *(const bf16x8*)(qp + 32);   // kk1: dh 32..63

    union { u32 u[4]; bf16x8 v; } ones;
    ones.u[0] = ones.u[1] = ones.u[2] = ones.u[3] = 0x3F803F80u;

    f32x4 o0 = {}, o1 = {}, o2 = {}, o3 = {};
    f32x4 osum = {};   // rowsum accumulator (cols redundant)

    for (int t = 0; t < 16; ++t) {
#pragma unroll
        for (int i = 0; i < 4; ++i) { llds16(stp[i], stl[i]); stp[i] += stinc; }
        __syncthreads();

        f32x4 s[8];
        __builtin_amdgcn_s_setprio(1);
#pragma unroll
        for (int kk = 0; kk < 2; ++kk) {
            int off = ((kk * 4 + quad) ^ sw) * 8;
            bf16x8 aq = kk == 0 ? q0 : q1;
#pragma unroll
            for (int ni = 0; ni < 8; ++ni) {
                bf16x8 bk = *(const bf16x8*)&Ks[(ni * 16 + lc) * 64 + off];
                if (kk == 0) {
                    f32x4 z = {0.f, 0.f, 0.f, 0.f};
                    s[ni] = MFMA(bk, aq, z, 0, 0, 0);
                } else {
                    s[ni] = MFMA(bk, aq, s[ni], 0, 0, 0);
                }
            }
        }
        __builtin_amdgcn_s_setprio(0);

        u32 px[8], py[8];
#pragma unroll
        for (int ni = 0; ni < 8; ++ni) {
            float p0 = __builtin_amdgcn_exp2f(s[ni][0]);
            float p1 = __builtin_amdgcn_exp2f(s[ni][1]);
            float p2 = __builtin_amdgcn_exp2f(s[ni][2]);
            float p3 = __builtin_amdgcn_exp2f(s[ni][3]);
            px[ni] = pk_bf16(p0, p1);
            py[ni] = pk_bf16(p2, p3);
        }

        __builtin_amdgcn_s_setprio(1);
#pragma unroll
        for (int kk = 0; kk < 4; ++kk) {
            int gq = kk * 4 + quad;
            bf16x8 bv0 = *(const bf16x8*)&Vs[( 0 + lc) * 128 + ((gq ^ lc) * 8)];
            bf16x8 bv1 = *(const bf16x8*)&Vs[(16 + lc) * 128 + ((gq ^ lc) * 8)];
            bf16x8 bv2 = *(const bf16x8*)&Vs[(32 + lc) * 128 + ((gq ^ lc) * 8)];
            bf16x8 bv3 = *(const bf16x8*)&Vs[(48 + lc) * 128 + ((gq ^ lc) * 8)];
            union { u32 u[4]; bf16x8 v; } a;
            a.u[0] = px[2 * kk]; a.u[1] = py[2 * kk];
            a.u[2] = px[2 * kk + 1]; a.u[3] = py[2 * kk + 1];
            o0 = MFMA(a.v, bv0, o0, 0, 0, 0); o1 = MFMA(a.v, bv1, o1, 0, 0, 0);
            o2 = MFMA(a.v, bv2, o2, 0, 0, 0); o3 = MFMA(a.v, bv3, o3, 0, 0, 0);
            osum = MFMA(a.v, ones.v, osum, 0, 0, 0);
        }
        __builtin_amdgcn_s_setprio(0);
        __syncthreads();  // Ks/Vs consumed before next tile's staging
    }

    f32x4 inv;
#pragma unroll
    for (int r = 0; r < 4; ++r) inv[r] = 1.f / osum[r];
#pragma unroll
    for (int nio = 0; nio < 4; ++nio) {
        const f32x4& ov = nio == 0 ? o0 : nio == 1 ? o1 : nio == 2 ? o2 : o3;
#pragma unroll
        for (int r = 0; r < 4; ++r) {
            int row = qt * 128 + wave * 16 + quad * 4 + r;
            O[((size_t)bh * L_ + row) * DH_ + nio * 16 + lc] = f2bf(ov[r] * inv[r]);
        }
    }
}

// -----------------------------------------------------------------------------
extern "C" void kernel_launch(void* const* d_in, const int* in_sizes, int n_in,
                              void* d_out, int out_size, void* d_ws, size_t ws_size,
                              hipStream_t stream) {
    (void)in_sizes; (void)n_in; (void)out_size; (void)ws_size;
    const float* x    = (const float*)d_in[0];
    const float* c    = (const float*)d_in[1];
    const float* Wq   = (const float*)d_in[2];
    const float* bq   = (const float*)d_in[3];
    const float* Wk   = (const float*)d_in[4];
    const float* bk   = (const float*)d_in[5];
    const float* Wv   = (const float*)d_in[6];
    const float* bv   = (const float*)d_in[7];
    const float* Wo   = (const float*)d_in[8];
    const float* bo   = (const float*)d_in[9];
    const float* W1   = (const float*)d_in[10];
    const float* b1   = (const float*)d_in[11];
    const float* W2   = (const float*)d_in[12];
    const float* b2   = (const float*)d_in[13];
    const float* Wada = (const float*)d_in[14];
    const float* bada = (const float*)d_in[15];

    char* w = (char*)d_ws;
    float*    ada  = (float*)(w + 0);                     // 49152 B
    ushort_t* Wqkv = (ushort_t*)(w + 49152);              // 6 MiB
    ushort_t* Wo_t = (ushort_t*)(w + 6340608);            // 2 MiB
    ushort_t* W1_t = (ushort_t*)(w + 8437760);            // 4 MiB
    ushort_t* W2_t = (ushort_t*)(w + 12632064);           // 4 MiB
    ushort_t* h    = (ushort_t*)(w + 16826368);           // 8 MiB (h / h2)
    ushort_t* Qb   = (ushort_t*)(w + 25214976);           // 8 MiB (Q)
    ushort_t* Kb   = (ushort_t*)(w + 33603584);           // 8 MiB (K)
    ushort_t* Ob   = (ushort_t*)(w + 41992192);           // 8 MiB (final O)
    ushort_t* Vtb  = (ushort_t*)(w + 50380800);           // 8 MiB (ada partials, then V^T)
    float*    x1   = (float*)(w + 58769408);              // 16 MiB (x1)
    ushort_t* m1   = Qb;            // MLP hidden (16 MiB = Qb+Kb, dead post-attn)
    float*    adap = (float*)Vtb;   // 786 KB split-k partials; dead before QKV gemm

    const int M = B_ * L_;  // 4096

    transpose_w_all<<<2048, 256, 0, stream>>>(Wq, Wk, Wv, Wo, W1, W2,
                                              Wqkv, Wo_t, W1_t, W2_t);

    ada_gemv<<<dim3(24, 16), 256, 0, stream>>>(c, Wada, adap);
    ada_reduce<<<24, 256, 0, stream>>>(adap, bada, ada);
    ln_mod<<<M, 256, 0, stream>>>(x, ada, 0, 1024, h);

    // QKV: Q,K -> (B,H,L,DH); V -> V^T (BH,DH,L) directly (transpose_v fused)
    EpiArgs e0 = {bq, bk, bv, Qb, Kb, Vtb, nullptr, nullptr, nullptr};
    gemm_bt<0><<<dim3(32, 24), 256, 0, stream>>>(h, Wqkv, M, 3072, D_, e0);

    // full-KV attention: final O, no partials, no merge; 8-wave blocks
    attn<<<512, 512, 0, stream>>>(Qb, Kb, Vtb, Ob);

    EpiArgs e1 = {bo, nullptr, nullptr, nullptr, nullptr, nullptr, x, ada + 2048, x1};
    gemm_bt64<2><<<dim3(64, 8), 256, 0, stream>>>(Ob, Wo_t, M, D_, D_, e1);

    ln_mod<<<M, 256, 0, stream>>>(x1, ada, 3072, 4096, h);

    // MLP1 (N=2048): 128x128 tile, grid 32x16 = 512 blocks = 2/CU (R6-best)
    EpiArgs e2 = {b1, nullptr, nullptr, m1, nullptr, nullptr, nullptr, nullptr, nullptr};
    gemm_bt<1><<<dim3(32, 16), 256, 0, stream>>>(h, W1_t, M, FF_, D_, e2);

    EpiArgs e3 = {b2, nullptr, nullptr, nullptr, nullptr, nullptr, x1, ada + 5120, (float*)d_out};
    gemm_bt64<2><<<dim3(64, 8), 256, 0, stream>>>(m1, W2_t, M, D_, FF_, e3);
}

// Round 11
// 309.190 us; speedup vs baseline: 1.0910x; 1.0254x over previous
//
#include <hip/hip_runtime.h>
#include <hip/hip_bf16.h>

typedef unsigned short ushort_t;
typedef __bf16 bf16x8 __attribute__((ext_vector_type(8)));
typedef float f32x4 __attribute__((ext_vector_type(4)));

typedef unsigned int u32;
typedef u32 __attribute__((address_space(1))) global_u32;
typedef u32 __attribute__((address_space(3))) lds_u32;

#define D_ 1024
#define L_ 2048
#define B_ 2
#define H_ 16
#define DH_ 64
#define FF_ 2048
#define ADA_ 6144
#define BHL_ (B_ * H_ * L_)

#define MFMA __builtin_amdgcn_mfma_f32_16x16x32_bf16

__device__ __forceinline__ ushort_t f2bf(float f) {
    union { float f; u32 u; } v; v.f = f;
    u32 r = v.u + 0x7fffu + ((v.u >> 16) & 1u);
    return (ushort_t)(r >> 16);
}

// packed 2xf32 -> 2xbf16 (v_cvt_pk_bf16_f32)
__device__ __forceinline__ u32 pk_bf16(float a, float b) {
    float2 f; f.x = a; f.y = b;
    __hip_bfloat162 t = __float22bfloat162_rn(f);
    union { __hip_bfloat162 b2; u32 u; } v; v.b2 = t; return v.u;
}

__device__ __forceinline__ void llds16(const ushort_t* src, ushort_t* dst) {
    __builtin_amdgcn_global_load_lds((global_u32*)src, (lds_u32*)dst, 16, 0, 0);
}

// ------- fused weight transpose+convert: all 6 weights, one dispatch ---------
__global__ void transpose_w_all(
    const float* __restrict__ Wq, const float* __restrict__ Wk,
    const float* __restrict__ Wv, const float* __restrict__ Wo,
    const float* __restrict__ W1, const float* __restrict__ W2,
    ushort_t* __restrict__ Wqkv, ushort_t* __restrict__ Wo_t,
    ushort_t* __restrict__ W1_t, ushort_t* __restrict__ W2_t) {
    __shared__ float tile[64][65];
    int id = blockIdx.x;
    const float* W; ushort_t* Wt; int K, N, ntx, lid;
    if (id < 1024) {
        int which = id >> 8; lid = id & 255; K = 1024; N = 1024; ntx = 16;
        W  = which == 0 ? Wq : which == 1 ? Wk : which == 2 ? Wv : Wo;
        Wt = which == 3 ? Wo_t : Wqkv + (size_t)which * 1024 * 1024;
    } else if (id < 1536) {
        lid = id - 1024; W = W1; Wt = W1_t; K = 1024; N = 2048; ntx = 32;
    } else {
        lid = id - 1536; W = W2; Wt = W2_t; K = 2048; N = 1024; ntx = 16;
    }
    int n0 = (lid % ntx) * 64, k0 = (lid / ntx) * 64;
    int t = threadIdx.x;
    for (int p = 0; p < 4; ++p) {
        int k = p * 16 + (t >> 4), nn = (t & 15) * 4;
        float4 v = *(const float4*)(W + (size_t)(k0 + k) * N + n0 + nn);
        tile[k][nn] = v.x; tile[k][nn + 1] = v.y; tile[k][nn + 2] = v.z; tile[k][nn + 3] = v.w;
    }
    __syncthreads();
    for (int p = 0; p < 4; ++p) {
        int n = p * 16 + (t >> 4), kk = (t & 15) * 4;
        ushort4 o;
        o.x = f2bf(tile[kk][n]); o.y = f2bf(tile[kk + 1][n]);
        o.z = f2bf(tile[kk + 2][n]); o.w = f2bf(tile[kk + 3][n]);
        *(ushort4*)(Wt + (size_t)(n0 + n) * K + k0 + kk) = o;
    }
}

// ---------------- ada = silu(c) @ Wada + bada: split-k GEMV ------------------
__global__ void ada_gemv(const float* __restrict__ c, const float* __restrict__ Wada,
                         float* __restrict__ partial) {
    int ks = blockIdx.y;
    int j = blockIdx.x * 256 + threadIdx.x;
    __shared__ float s0[64], s1[64];
    if (threadIdx.x < 64) {
        float v = c[ks * 64 + threadIdx.x];
        s0[threadIdx.x] = v / (1.f + __expf(-v));
        v = c[D_ + ks * 64 + threadIdx.x];
        s1[threadIdx.x] = v / (1.f + __expf(-v));
    }
    __syncthreads();
    float a0 = 0.f, a1 = 0.f;
#pragma unroll 8
    for (int d = 0; d < 64; ++d) {
        float w = Wada[(size_t)(ks * 64 + d) * ADA_ + j];
        a0 = fmaf(s0[d], w, a0);
        a1 = fmaf(s1[d], w, a1);
    }
    partial[(size_t)(ks * 2 + 0) * ADA_ + j] = a0;
    partial[(size_t)(ks * 2 + 1) * ADA_ + j] = a1;
}

__global__ void ada_reduce(const float* __restrict__ partial,
                           const float* __restrict__ bada, float* __restrict__ ada) {
    int j = blockIdx.x * 256 + threadIdx.x;
    float a0 = bada[j], a1 = bada[j];
#pragma unroll
    for (int ks = 0; ks < 16; ++ks) {
        a0 += partial[(size_t)(ks * 2 + 0) * ADA_ + j];
        a1 += partial[(size_t)(ks * 2 + 1) * ADA_ + j];
    }
    ada[j] = a0;
    ada[ADA_ + j] = a1;
}

// ---------------- LayerNorm + modulation -> bf16 -----------------------------
__global__ void ln_mod(const float* __restrict__ x, const float* __restrict__ ada,
                       int so, int co, ushort_t* __restrict__ out) {
    int row = blockIdx.x;
    int b = row >> 11;
    float4 v = ((const float4*)(x + (size_t)row * D_))[threadIdx.x];
    float sum = v.x + v.y + v.z + v.w;
    float sq = v.x * v.x + v.y * v.y + v.z * v.z + v.w * v.w;
    for (int off = 32; off; off >>= 1) { sum += __shfl_down(sum, off); sq += __shfl_down(sq, off); }
    __shared__ float sa[4], sb[4];
    int wave = threadIdx.x >> 6, lane = threadIdx.x & 63;
    if (lane == 0) { sa[wave] = sum; sb[wave] = sq; }
    __syncthreads();
    sum = sa[0] + sa[1] + sa[2] + sa[3];
    sq = sb[0] + sb[1] + sb[2] + sb[3];
    float mean = sum * (1.f / 1024.f);
    float var = sq * (1.f / 1024.f) - mean * mean;
    float rstd = rsqrtf(var + 1e-6f);
    int d = threadIdx.x * 4;
    const float* shf = ada + (size_t)b * ADA_ + so;
    const float* scf = ada + (size_t)b * ADA_ + co;
    uint2 ov;
    ov.x = pk_bf16((v.x - mean) * rstd * (1.f + scf[d + 0]) + shf[d + 0],
                   (v.y - mean) * rstd * (1.f + scf[d + 1]) + shf[d + 1]);
    ov.y = pk_bf16((v.z - mean) * rstd * (1.f + scf[d + 2]) + shf[d + 2],
                   (v.w - mean) * rstd * (1.f + scf[d + 3]) + shf[d + 3]);
    *(uint2*)(out + (size_t)row * D_ + d) = ov;
}

// ---------------- GEMM epilogues ---------------------------------------------
struct EpiArgs {
    const float* bias0; const float* bias1; const float* bias2;
    ushort_t* o0; ushort_t* o1; ushort_t* o2;
    const float* resid; const float* gate;
    float* fout;
};

template <int EPI>
__device__ __forceinline__ void epi_store(float v, int m, int n, int N, const EpiArgs& e) {
    if (EPI == 0) {  // Q/K -> (B,H,L,DH) bf16; Q pre-scaled by log2(e)/8
        int which = n >> 10, cc = n & 1023;
        const float* bias = which == 0 ? e.bias0 : e.bias1;
        ushort_t* ob = which == 0 ? e.o0 : e.o1;
        v += bias[cc];
        if (which == 0) v *= 0.18033688f;  // (1/8) * log2(e): softmax uses exp2
        int b = m >> 11, l = m & 2047, h = cc >> 6, dh = cc & 63;
        ob[(((size_t)(b * H_ + h) * L_) + l) * DH_ + dh] = f2bf(v);
    } else if (EPI == 1) {  // bias + exact GELU -> bf16
        v += e.bias0[n];
        v = 0.5f * v * (1.f + erff(v * 0.70710678118f));
        e.o0[(size_t)m * N + n] = f2bf(v);
    } else {  // residual + gate -> fp32
        int b = m >> 11;
        e.fout[(size_t)m * N + n] =
            e.resid[(size_t)m * N + n] + e.gate[(size_t)b * ADA_ + n] * (v + e.bias0[n]);
    }
}

template <int EPI>
__device__ __forceinline__ void st4(const f32x4& cc, int mb, int n, int N, const EpiArgs& e) {
    if (EPI == 0 && n >= 2048) {
        // V: direct transpose write -> (BH, DH, L) bf16. mb..mb+3 are 4
        // consecutive l within one batch -> contiguous ushort4 in V^T.
        int ccn = n & 1023;
        float b4 = e.bias2[ccn];
        int b = mb >> 11, l0 = mb & 2047, h = ccn >> 6, dh = ccn & 63;
        ushort4 o;
        o.x = f2bf(cc[0] + b4); o.y = f2bf(cc[1] + b4);
        o.z = f2bf(cc[2] + b4); o.w = f2bf(cc[3] + b4);
        *(ushort4*)(e.o2 + ((size_t)(b * H_ + h) * DH_ + dh) * L_ + l0) = o;
        return;
    }
#pragma unroll
    for (int r = 0; r < 4; ++r) epi_store<EPI>(cc[r], mb + r, n, N, e);
}

// ---------------- GEMM 128x128 tile (QKV) ------------------------------------
template <int EPI>
__global__ __launch_bounds__(256, 2) void gemm_bt(
    const ushort_t* __restrict__ A, const ushort_t* __restrict__ Bt,
    int M, int N, int K, EpiArgs e) {
    __shared__ ushort_t As[128 * 64];
    __shared__ ushort_t Bs[128 * 64];
    int m0 = blockIdx.x * 128, n0 = blockIdx.y * 128;
    int tid = threadIdx.x, wave = tid >> 6, lane = tid & 63;
    int quad = lane >> 4, lc = lane & 15;
    int wm = (wave & 1) * 64, wn = (wave >> 1) * 64;
    int srow = lane >> 3, sg = lane & 7;
    int sw = lc & 7;

    const ushort_t* stp[8];
    ushort_t* stl[8];
#pragma unroll
    for (int i = 0; i < 8; ++i) {
        int chunk = wave * 8 + i;
        int c = chunk & 15;
        int row = c * 8 + srow;
        stp[i] = (chunk < 16 ? A + (size_t)(m0 + row) * K
                             : Bt + (size_t)(n0 + row) * K) + (sg ^ srow) * 8;
        stl[i] = (chunk < 16 ? As : Bs) + c * 512 + lane * 8;
    }

    f32x4 c00 = {}, c01 = {}, c02 = {}, c03 = {};
    f32x4 c10 = {}, c11 = {}, c12 = {}, c13 = {};
    f32x4 c20 = {}, c21 = {}, c22 = {}, c23 = {};
    f32x4 c30 = {}, c31 = {}, c32 = {}, c33 = {};

    for (int k0 = 0; k0 < K; k0 += 64) {
#pragma unroll
        for (int i = 0; i < 8; ++i) { llds16(stp[i], stl[i]); stp[i] += 64; }
        __syncthreads();
#pragma unroll
        for (int kk = 0; kk < 2; ++kk) {
            int off = ((kk * 4 + quad) ^ sw) * 8;
            bf16x8 a0 = *(const bf16x8*)&As[(wm +  0 + lc) * 64 + off];
            bf16x8 a1 = *(const bf16x8*)&As[(wm + 16 + lc) * 64 + off];
            bf16x8 a2 = *(const bf16x8*)&As[(wm + 32 + lc) * 64 + off];
            bf16x8 a3 = *(const bf16x8*)&As[(wm + 48 + lc) * 64 + off];
            bf16x8 b0 = *(const bf16x8*)&Bs[(wn +  0 + lc) * 64 + off];
            bf16x8 b1 = *(const bf16x8*)&Bs[(wn + 16 + lc) * 64 + off];
            bf16x8 b2 = *(const bf16x8*)&Bs[(wn + 32 + lc) * 64 + off];
            bf16x8 b3 = *(const bf16x8*)&Bs[(wn + 48 + lc) * 64 + off];
            c00 = MFMA(a0, b0, c00, 0, 0, 0); c01 = MFMA(a0, b1, c01, 0, 0, 0);
            c02 = MFMA(a0, b2, c02, 0, 0, 0); c03 = MFMA(a0, b3, c03, 0, 0, 0);
            c10 = MFMA(a1, b0, c10, 0, 0, 0); c11 = MFMA(a1, b1, c11, 0, 0, 0);
            c12 = MFMA(a1, b2, c12, 0, 0, 0); c13 = MFMA(a1, b3, c13, 0, 0, 0);
            c20 = MFMA(a2, b0, c20, 0, 0, 0); c21 = MFMA(a2, b1, c21, 0, 0, 0);
            c22 = MFMA(a2, b2, c22, 0, 0, 0); c23 = MFMA(a2, b3, c23, 0, 0, 0);
            c30 = MFMA(a3, b0, c30, 0, 0, 0); c31 = MFMA(a3, b1, c31, 0, 0, 0);
            c32 = MFMA(a3, b2, c32, 0, 0, 0); c33 = MFMA(a3, b3, c33, 0, 0, 0);
        }
        __syncthreads();
    }

    int mb = m0 + wm + quad * 4, nb = n0 + wn + lc;
    st4<EPI>(c00, mb +  0, nb +  0, N, e); st4<EPI>(c01, mb +  0, nb + 16, N, e);
    st4<EPI>(c02, mb +  0, nb + 32, N, e); st4<EPI>(c03, mb +  0, nb + 48, N, e);
    st4<EPI>(c10, mb + 16, nb +  0, N, e); st4<EPI>(c11, mb + 16, nb + 16, N, e);
    st4<EPI>(c12, mb + 16, nb + 32, N, e); st4<EPI>(c13, mb + 16, nb + 48, N, e);
    st4<EPI>(c20, mb + 32, nb +  0, N, e); st4<EPI>(c21, mb + 32, nb + 16, N, e);
    st4<EPI>(c22, mb + 32, nb + 32, N, e); st4<EPI>(c23, mb + 32, nb + 48, N, e);
    st4<EPI>(c30, mb + 48, nb +  0, N, e); st4<EPI>(c31, mb + 48, nb + 16, N, e);
    st4<EPI>(c32, mb + 48, nb + 32, N, e); st4<EPI>(c33, mb + 48, nb + 48, N, e);
}

// ---------------- GEMM 64x128 tile (O-proj, MLP1, MLP2) ----------------------
template <int EPI>
__global__ __launch_bounds__(256, 2) void gemm_bt64(
    const ushort_t* __restrict__ A, const ushort_t* __restrict__ Bt,
    int M, int N, int K, EpiArgs e) {
    __shared__ ushort_t As[64 * 64];    // 8 KB
    __shared__ ushort_t Bs[128 * 64];   // 16 KB
    int m0 = blockIdx.x * 64, n0 = blockIdx.y * 128;
    int tid = threadIdx.x, wave = tid >> 6, lane = tid & 63;
    int quad = lane >> 4, lc = lane & 15;
    int wn = wave * 32;
    int srow = lane >> 3, sg = lane & 7;
    int sw = lc & 7;

    const ushort_t* stp[6];
    ushort_t* stl[6];
#pragma unroll
    for (int i = 0; i < 6; ++i) {
        int chunk = wave * 6 + i;
        if (chunk < 8) {
            int row = chunk * 8 + srow;
            stp[i] = A + (size_t)(m0 + row) * K + (sg ^ srow) * 8;
            stl[i] = &As[chunk * 512 + lane * 8];
        } else {
            int c = chunk - 8;
            int row = c * 8 + srow;
            stp[i] = Bt + (size_t)(n0 + row) * K + (sg ^ srow) * 8;
            stl[i] = &Bs[c * 512 + lane * 8];
        }
    }

    f32x4 c00 = {}, c01 = {};
    f32x4 c10 = {}, c11 = {};
    f32x4 c20 = {}, c21 = {};
    f32x4 c30 = {}, c31 = {};

    for (int k0 = 0; k0 < K; k0 += 64) {
#pragma unroll
        for (int i = 0; i < 6; ++i) { llds16(stp[i], stl[i]); stp[i] += 64; }
        __syncthreads();
#pragma unroll
        for (int kk = 0; kk < 2; ++kk) {
            int off = ((kk * 4 + quad) ^ sw) * 8;
            bf16x8 a0 = *(const bf16x8*)&As[( 0 + lc) * 64 + off];
            bf16x8 a1 = *(const bf16x8*)&As[(16 + lc) * 64 + off];
            bf16x8 a2 = *(const bf16x8*)&As[(32 + lc) * 64 + off];
            bf16x8 a3 = *(const bf16x8*)&As[(48 + lc) * 64 + off];
            bf16x8 b0 = *(const bf16x8*)&Bs[(wn +  0 + lc) * 64 + off];
            bf16x8 b1 = *(const bf16x8*)&Bs[(wn + 16 + lc) * 64 + off];
            c00 = MFMA(a0, b0, c00, 0, 0, 0); c01 = MFMA(a0, b1, c01, 0, 0, 0);
            c10 = MFMA(a1, b0, c10, 0, 0, 0); c11 = MFMA(a1, b1, c11, 0, 0, 0);
            c20 = MFMA(a2, b0, c20, 0, 0, 0); c21 = MFMA(a2, b1, c21, 0, 0, 0);
            c30 = MFMA(a3, b0, c30, 0, 0, 0); c31 = MFMA(a3, b1, c31, 0, 0, 0);
        }
        __syncthreads();
    }

    int mb = m0 + quad * 4, nb = n0 + wn + lc;
    st4<EPI>(c00, mb +  0, nb + 0, N, e); st4<EPI>(c01, mb +  0, nb + 16, N, e);
    st4<EPI>(c10, mb + 16, nb + 0, N, e); st4<EPI>(c11, mb + 16, nb + 16, N, e);
    st4<EPI>(c20, mb + 32, nb + 0, N, e); st4<EPI>(c21, mb + 32, nb + 16, N, e);
    st4<EPI>(c30, mb + 48, nb + 0, N, e); st4<EPI>(c31, mb + 48, nb + 16, N, e);
}

// ---------------- flash attention v14 (best measured): 8-wave, single buf ----
__global__ __launch_bounds__(512, 4) void attn(
    const ushort_t* __restrict__ Q, const ushort_t* __restrict__ Kx,
    const ushort_t* __restrict__ Vt, ushort_t* __restrict__ O) {
    __shared__ ushort_t Ks[128 * 64];     // 16 KB
    __shared__ ushort_t Vs[64 * 128];     // 16 KB
    int id = blockIdx.x;
    int bh = ((id & 7) << 2) + ((id >> 3) & 3);  // 4 bh per XCD class
    int qt = id >> 5;                            // 16 q-tiles of 128 rows
    const ushort_t* Qg = Q + ((size_t)bh * L_ + qt * 128) * DH_;
    const ushort_t* Kg = Kx + (size_t)bh * L_ * DH_;
    const ushort_t* Vg = Vt + (size_t)bh * DH_ * L_;
    int tid = threadIdx.x, wave = tid >> 6, lane = tid & 63;
    int quad = lane >> 4, lc = lane & 15;
    int sw = lc & 7;
    int srow = lane >> 3, sg = lane & 7;

    const ushort_t* stp[4];
    ushort_t* stl[4];
    int stinc;
    if (wave < 4) {
        stinc = 128 * DH_;
#pragma unroll
        for (int i = 0; i < 4; ++i) {
            int chunk = wave * 4 + i;            // 0..15
            int slot = chunk * 8 + srow;         // LDS row (slot)
            int s5 = slot & 31;                  // within-32 position
            int sig = (slot & ~31) + ((s5 & 15) >> 2) * 8 + (s5 & 3) + (s5 >> 4) * 4;
            stp[i] = Kg + (size_t)sig * DH_ + (sg ^ srow) * 8;
            stl[i] = &Ks[chunk * 512 + lane * 8];
        }
    } else {
        stinc = 128;
#pragma unroll
        for (int i = 0; i < 4; ++i) {
            int c2 = (wave - 4) * 4 + i;         // 0..15
            int row = c2 * 4 + (lane >> 4);
            int g = (lane & 15) ^ (row & 15);
            stp[i] = Vg + (size_t)row * L_ + g * 8;
            stl[i] = &Vs[c2 * 512 + lane * 8];
        }
    }

    const ushort_t* qp = Qg + (size_t)(wave * 16 + lc) * DH_ + quad * 8;
    bf16x8 q0 = *(const bf16x8*)(qp);        // kk0: dh 0..31 (quad-sliced)
    bf16x8 q1 = *(const bf16x8*)(qp + 32);   // kk1: dh 32..63

    union { u32 u[4]; bf16x8 v; } ones;
    ones.u[0] = ones.u[1] = ones.u[2] = ones.u[3] = 0x3F803F80u;

    f32x4 o0 = {}, o1 = {}, o2 = {}, o3 = {};
    f32x4 osum = {};   // rowsum accumulator (cols redundant)

    for (int t = 0; t < 16; ++t) {
#pragma unroll
        for (int i = 0; i < 4; ++i) { llds16(stp[i], stl[i]); stp[i] += stinc; }
        __syncthreads();

        f32x4 s[8];
        __builtin_amdgcn_s_setprio(1);
#pragma unroll
        for (int kk = 0; kk < 2; ++kk) {
            int off = ((kk * 4 + quad) ^ sw) * 8;
            bf16x8 aq = kk == 0 ? q0 : q1;
#pragma unroll
            for (int ni = 0; ni < 8; ++ni) {
                bf16x8 bk = *(const bf16x8*)&Ks[(ni * 16 + lc) * 64 + off];
                if (kk == 0) {
                    f32x4 z = {0.f, 0.f, 0.f, 0.f};
                    s[ni] = MFMA(bk, aq, z, 0, 0, 0);
                } else {
                    s[ni] = MFMA(bk, aq, s[ni], 0, 0, 0);
                }
            }
        }
        __builtin_amdgcn_s_setprio(0);

        u32 px[8], py[8];
#pragma unroll
        for (int ni = 0; ni < 8; ++ni) {
            float p0 = __builtin_amdgcn_exp2f(s[ni][0]);
            float p1 = __builtin_amdgcn_exp2f(s[ni][1]);
            float p2 = __builtin_amdgcn_exp2f(s[ni][2]);
            float p3 = __builtin_amdgcn_exp2f(s[ni][3]);
            px[ni] = pk_bf16(p0, p1);
            py[ni] = pk_bf16(p2, p3);
        }

        __builtin_amdgcn_s_setprio(1);
#pragma unroll
        for (int kk = 0; kk < 4; ++kk) {
            int gq = kk * 4 + quad;
            bf16x8 bv0 = *(const bf16x8*)&Vs[( 0 + lc) * 128 + ((gq ^ lc) * 8)];
            bf16x8 bv1 = *(const bf16x8*)&Vs[(16 + lc) * 128 + ((gq ^ lc) * 8)];
            bf16x8 bv2 = *(const bf16x8*)&Vs[(32 + lc) * 128 + ((gq ^ lc) * 8)];
            bf16x8 bv3 = *(const bf16x8*)&Vs[(48 + lc) * 128 + ((gq ^ lc) * 8)];
            union { u32 u[4]; bf16x8 v; } a;
            a.u[0] = px[2 * kk]; a.u[1] = py[2 * kk];
            a.u[2] = px[2 * kk + 1]; a.u[3] = py[2 * kk + 1];
            o0 = MFMA(a.v, bv0, o0, 0, 0, 0); o1 = MFMA(a.v, bv1, o1, 0, 0, 0);
            o2 = MFMA(a.v, bv2, o2, 0, 0, 0); o3 = MFMA(a.v, bv3, o3, 0, 0, 0);
            osum = MFMA(a.v, ones.v, osum, 0, 0, 0);
        }
        __builtin_amdgcn_s_setprio(0);
        __syncthreads();  // Ks/Vs consumed before next tile's staging
    }

    f32x4 inv;
#pragma unroll
    for (int r = 0; r < 4; ++r) inv[r] = 1.f / osum[r];
#pragma unroll
    for (int nio = 0; nio < 4; ++nio) {
        const f32x4& ov = nio == 0 ? o0 : nio == 1 ? o1 : nio == 2 ? o2 : o3;
#pragma unroll
        for (int r = 0; r < 4; ++r) {
            int row = qt * 128 + wave * 16 + quad * 4 + r;
            O[((size_t)bh * L_ + row) * DH_ + nio * 16 + lc] = f2bf(ov[r] * inv[r]);
        }
    }
}

// -----------------------------------------------------------------------------
extern "C" void kernel_launch(void* const* d_in, const int* in_sizes, int n_in,
                              void* d_out, int out_size, void* d_ws, size_t ws_size,
                              hipStream_t stream) {
    (void)in_sizes; (void)n_in; (void)out_size; (void)ws_size;
    const float* x    = (const float*)d_in[0];
    const float* c    = (const float*)d_in[1];
    const float* Wq   = (const float*)d_in[2];
    const float* bq   = (const float*)d_in[3];
    const float* Wk   = (const float*)d_in[4];
    const float* bk   = (const float*)d_in[5];
    const float* Wv   = (const float*)d_in[6];
    const float* bv   = (const float*)d_in[7];
    const float* Wo   = (const float*)d_in[8];
    const float* bo   = (const float*)d_in[9];
    const float* W1   = (const float*)d_in[10];
    const float* b1   = (const float*)d_in[11];
    const float* W2   = (const float*)d_in[12];
    const float* b2   = (const float*)d_in[13];
    const float* Wada = (const float*)d_in[14];
    const float* bada = (const float*)d_in[15];

    char* w = (char*)d_ws;
    float*    ada  = (float*)(w + 0);                     // 49152 B
    ushort_t* Wqkv = (ushort_t*)(w + 49152);              // 6 MiB
    ushort_t* Wo_t = (ushort_t*)(w + 6340608);            // 2 MiB
    ushort_t* W1_t = (ushort_t*)(w + 8437760);            // 4 MiB
    ushort_t* W2_t = (ushort_t*)(w + 12632064);           // 4 MiB
    ushort_t* h    = (ushort_t*)(w + 16826368);           // 8 MiB (h / h2)
    ushort_t* Qb   = (ushort_t*)(w + 25214976);           // 8 MiB (Q)
    ushort_t* Kb   = (ushort_t*)(w + 33603584);           // 8 MiB (K)
    ushort_t* Ob   = (ushort_t*)(w + 41992192);           // 8 MiB (final O)
    ushort_t* Vtb  = (ushort_t*)(w + 50380800);           // 8 MiB (ada partials, then V^T)
    float*    x1   = (float*)(w + 58769408);              // 16 MiB (x1)
    ushort_t* m1   = Qb;            // MLP hidden (16 MiB = Qb+Kb, dead post-attn)
    float*    adap = (float*)Vtb;   // 786 KB split-k partials; dead before QKV gemm

    const int M = B_ * L_;  // 4096

    transpose_w_all<<<2048, 256, 0, stream>>>(Wq, Wk, Wv, Wo, W1, W2,
                                              Wqkv, Wo_t, W1_t, W2_t);

    ada_gemv<<<dim3(24, 16), 256, 0, stream>>>(c, Wada, adap);
    ada_reduce<<<24, 256, 0, stream>>>(adap, bada, ada);
    ln_mod<<<M, 256, 0, stream>>>(x, ada, 0, 1024, h);

    // QKV: Q,K -> (B,H,L,DH); V -> V^T (BH,DH,L) directly (transpose_v fused)
    EpiArgs e0 = {bq, bk, bv, Qb, Kb, Vtb, nullptr, nullptr, nullptr};
    gemm_bt<0><<<dim3(32, 24), 256, 0, stream>>>(h, Wqkv, M, 3072, D_, e0);

    // full-KV attention: final O, no partials, no merge; 8-wave blocks
    attn<<<512, 512, 0, stream>>>(Qb, Kb, Vtb, Ob);

    EpiArgs e1 = {bo, nullptr, nullptr, nullptr, nullptr, nullptr, x, ada + 2048, x1};
    gemm_bt64<2><<<dim3(64, 8), 256, 0, stream>>>(Ob, Wo_t, M, D_, D_, e1);

    ln_mod<<<M, 256, 0, stream>>>(x1, ada, 3072, 4096, h);

    // MLP1 (N=2048): 64x128 tile, grid (64,16) = 1024 blocks = 4/CU (R6-best:
    // paired runs show this beats the 128^2 tile by ~6-9 us at this shape)
    EpiArgs e2 = {b1, nullptr, nullptr, m1, nullptr, nullptr, nullptr, nullptr, nullptr};
    gemm_bt64<1><<<dim3(64, 16), 256, 0, stream>>>(h, W1_t, M, FF_, D_, e2);

    EpiArgs e3 = {b2, nullptr, nullptr, nullptr, nullptr, nullptr, x1, ada + 5120, (float*)d_out};
    gemm_bt64<2><<<dim3(64, 8), 256, 0, stream>>>(m1, W2_t, M, D_, FF_, e3);
}

// Round 12
// 298.293 us; speedup vs baseline: 1.1309x; 1.0365x over previous
//
#include <hip/hip_runtime.h>
#include <hip/hip_bf16.h>

typedef unsigned short ushort_t;
typedef __bf16 bf16x8 __attribute__((ext_vector_type(8)));
typedef float f32x4 __attribute__((ext_vector_type(4)));

typedef unsigned int u32;
typedef u32 __attribute__((address_space(1))) global_u32;
typedef u32 __attribute__((address_space(3))) lds_u32;

#define D_ 1024
#define L_ 2048
#define B_ 2
#define H_ 16
#define DH_ 64
#define FF_ 2048
#define ADA_ 6144
#define BHL_ (B_ * H_ * L_)

#define MFMA __builtin_amdgcn_mfma_f32_16x16x32_bf16

__device__ __forceinline__ ushort_t f2bf(float f) {
    union { float f; u32 u; } v; v.f = f;
    u32 r = v.u + 0x7fffu + ((v.u >> 16) & 1u);
    return (ushort_t)(r >> 16);
}

// packed 2xf32 -> 2xbf16 (v_cvt_pk_bf16_f32)
__device__ __forceinline__ u32 pk_bf16(float a, float b) {
    float2 f; f.x = a; f.y = b;
    __hip_bfloat162 t = __float22bfloat162_rn(f);
    union { __hip_bfloat162 b2; u32 u; } v; v.b2 = t; return v.u;
}

__device__ __forceinline__ void llds16(const ushort_t* src, ushort_t* dst) {
    __builtin_amdgcn_global_load_lds((global_u32*)src, (lds_u32*)dst, 16, 0, 0);
}

// ------- fused weight transpose+convert: all 6 weights, one dispatch ---------
__global__ void transpose_w_all(
    const float* __restrict__ Wq, const float* __restrict__ Wk,
    const float* __restrict__ Wv, const float* __restrict__ Wo,
    const float* __restrict__ W1, const float* __restrict__ W2,
    ushort_t* __restrict__ Wqkv, ushort_t* __restrict__ Wo_t,
    ushort_t* __restrict__ W1_t, ushort_t* __restrict__ W2_t) {
    __shared__ float tile[64][65];
    int id = blockIdx.x;
    const float* W; ushort_t* Wt; int K, N, ntx, lid;
    if (id < 1024) {
        int which = id >> 8; lid = id & 255; K = 1024; N = 1024; ntx = 16;
        W  = which == 0 ? Wq : which == 1 ? Wk : which == 2 ? Wv : Wo;
        Wt = which == 3 ? Wo_t : Wqkv + (size_t)which * 1024 * 1024;
    } else if (id < 1536) {
        lid = id - 1024; W = W1; Wt = W1_t; K = 1024; N = 2048; ntx = 32;
    } else {
        lid = id - 1536; W = W2; Wt = W2_t; K = 2048; N = 1024; ntx = 16;
    }
    int n0 = (lid % ntx) * 64, k0 = (lid / ntx) * 64;
    int t = threadIdx.x;
    for (int p = 0; p < 4; ++p) {
        int k = p * 16 + (t >> 4), nn = (t & 15) * 4;
        float4 v = *(const float4*)(W + (size_t)(k0 + k) * N + n0 + nn);
        tile[k][nn] = v.x; tile[k][nn + 1] = v.y; tile[k][nn + 2] = v.z; tile[k][nn + 3] = v.w;
    }
    __syncthreads();
    for (int p = 0; p < 4; ++p) {
        int n = p * 16 + (t >> 4), kk = (t & 15) * 4;
        ushort4 o;
        o.x = f2bf(tile[kk][n]); o.y = f2bf(tile[kk + 1][n]);
        o.z = f2bf(tile[kk + 2][n]); o.w = f2bf(tile[kk + 3][n]);
        *(ushort4*)(Wt + (size_t)(n0 + n) * K + k0 + kk) = o;
    }
}

// ---------------- ada = silu(c) @ Wada + bada: split-k GEMV ------------------
__global__ void ada_gemv(const float* __restrict__ c, const float* __restrict__ Wada,
                         float* __restrict__ partial) {
    int ks = blockIdx.y;
    int j = blockIdx.x * 256 + threadIdx.x;
    __shared__ float s0[64], s1[64];
    if (threadIdx.x < 64) {
        float v = c[ks * 64 + threadIdx.x];
        s0[threadIdx.x] = v / (1.f + __expf(-v));
        v = c[D_ + ks * 64 + threadIdx.x];
        s1[threadIdx.x] = v / (1.f + __expf(-v));
    }
    __syncthreads();
    float a0 = 0.f, a1 = 0.f;
#pragma unroll 8
    for (int d = 0; d < 64; ++d) {
        float w = Wada[(size_t)(ks * 64 + d) * ADA_ + j];
        a0 = fmaf(s0[d], w, a0);
        a1 = fmaf(s1[d], w, a1);
    }
    partial[(size_t)(ks * 2 + 0) * ADA_ + j] = a0;
    partial[(size_t)(ks * 2 + 1) * ADA_ + j] = a1;
}

__global__ void ada_reduce(const float* __restrict__ partial,
                           const float* __restrict__ bada, float* __restrict__ ada) {
    int j = blockIdx.x * 256 + threadIdx.x;
    float a0 = bada[j], a1 = bada[j];
#pragma unroll
    for (int ks = 0; ks < 16; ++ks) {
        a0 += partial[(size_t)(ks * 2 + 0) * ADA_ + j];
        a1 += partial[(size_t)(ks * 2 + 1) * ADA_ + j];
    }
    ada[j] = a0;
    ada[ADA_ + j] = a1;
}

// ---------------- LayerNorm + modulation -> bf16 -----------------------------
__global__ void ln_mod(const float* __restrict__ x, const float* __restrict__ ada,
                       int so, int co, ushort_t* __restrict__ out) {
    int row = blockIdx.x;
    int b = row >> 11;
    float4 v = ((const float4*)(x + (size_t)row * D_))[threadIdx.x];
    float sum = v.x + v.y + v.z + v.w;
    float sq = v.x * v.x + v.y * v.y + v.z * v.z + v.w * v.w;
    for (int off = 32; off; off >>= 1) { sum += __shfl_down(sum, off); sq += __shfl_down(sq, off); }
    __shared__ float sa[4], sb[4];
    int wave = threadIdx.x >> 6, lane = threadIdx.x & 63;
    if (lane == 0) { sa[wave] = sum; sb[wave] = sq; }
    __syncthreads();
    sum = sa[0] + sa[1] + sa[2] + sa[3];
    sq = sb[0] + sb[1] + sb[2] + sb[3];
    float mean = sum * (1.f / 1024.f);
    float var = sq * (1.f / 1024.f) - mean * mean;
    float rstd = rsqrtf(var + 1e-6f);
    int d = threadIdx.x * 4;
    const float* shf = ada + (size_t)b * ADA_ + so;
    const float* scf = ada + (size_t)b * ADA_ + co;
    uint2 ov;
    ov.x = pk_bf16((v.x - mean) * rstd * (1.f + scf[d + 0]) + shf[d + 0],
                   (v.y - mean) * rstd * (1.f + scf[d + 1]) + shf[d + 1]);
    ov.y = pk_bf16((v.z - mean) * rstd * (1.f + scf[d + 2]) + shf[d + 2],
                   (v.w - mean) * rstd * (1.f + scf[d + 3]) + shf[d + 3]);
    *(uint2*)(out + (size_t)row * D_ + d) = ov;
}

// ---------------- GEMM epilogues ---------------------------------------------
struct EpiArgs {
    const float* bias0; const float* bias1; const float* bias2;
    ushort_t* o0; ushort_t* o1; ushort_t* o2;
    const float* resid; const float* gate;
    float* fout;
};

template <int EPI>
__device__ __forceinline__ void epi_store(float v, int m, int n, int N, const EpiArgs& e) {
    if (EPI == 0) {  // Q/K -> (B,H,L,DH) bf16; Q pre-scaled by log2(e)/8
        int which = n >> 10, cc = n & 1023;
        const float* bias = which == 0 ? e.bias0 : e.bias1;
        ushort_t* ob = which == 0 ? e.o0 : e.o1;
        v += bias[cc];
        if (which == 0) v *= 0.18033688f;  // (1/8) * log2(e): softmax uses exp2
        int b = m >> 11, l = m & 2047, h = cc >> 6, dh = cc & 63;
        ob[(((size_t)(b * H_ + h) * L_) + l) * DH_ + dh] = f2bf(v);
    } else if (EPI == 1) {  // bias + exact GELU -> bf16
        v += e.bias0[n];
        v = 0.5f * v * (1.f + erff(v * 0.70710678118f));
        e.o0[(size_t)m * N + n] = f2bf(v);
    } else {  // residual + gate -> fp32
        int b = m >> 11;
        e.fout[(size_t)m * N + n] =
            e.resid[(size_t)m * N + n] + e.gate[(size_t)b * ADA_ + n] * (v + e.bias0[n]);
    }
}

template <int EPI>
__device__ __forceinline__ void st4(const f32x4& cc, int mb, int n, int N, const EpiArgs& e) {
    if (EPI == 0 && n >= 2048) {
        // V: direct transpose write -> (BH, DH, L) bf16. mb..mb+3 are 4
        // consecutive l within one batch -> contiguous ushort4 in V^T.
        int ccn = n & 1023;
        float b4 = e.bias2[ccn];
        int b = mb >> 11, l0 = mb & 2047, h = ccn >> 6, dh = ccn & 63;
        ushort4 o;
        o.x = f2bf(cc[0] + b4); o.y = f2bf(cc[1] + b4);
        o.z = f2bf(cc[2] + b4); o.w = f2bf(cc[3] + b4);
        *(ushort4*)(e.o2 + ((size_t)(b * H_ + h) * DH_ + dh) * L_ + l0) = o;
        return;
    }
#pragma unroll
    for (int r = 0; r < 4; ++r) epi_store<EPI>(cc[r], mb + r, n, N, e);
}

// ---------------- GEMM 128x128 tile (QKV) ------------------------------------
template <int EPI>
__global__ __launch_bounds__(256, 2) void gemm_bt(
    const ushort_t* __restrict__ A, const ushort_t* __restrict__ Bt,
    int M, int N, int K, EpiArgs e) {
    __shared__ ushort_t As[128 * 64];
    __shared__ ushort_t Bs[128 * 64];
    int m0 = blockIdx.x * 128, n0 = blockIdx.y * 128;
    int tid = threadIdx.x, wave = tid >> 6, lane = tid & 63;
    int quad = lane >> 4, lc = lane & 15;
    int wm = (wave & 1) * 64, wn = (wave >> 1) * 64;
    int srow = lane >> 3, sg = lane & 7;
    int sw = lc & 7;

    const ushort_t* stp[8];
    ushort_t* stl[8];
#pragma unroll
    for (int i = 0; i < 8; ++i) {
        int chunk = wave * 8 + i;
        int c = chunk & 15;
        int row = c * 8 + srow;
        stp[i] = (chunk < 16 ? A + (size_t)(m0 + row) * K
                             : Bt + (size_t)(n0 + row) * K) + (sg ^ srow) * 8;
        stl[i] = (chunk < 16 ? As : Bs) + c * 512 + lane * 8;
    }

    f32x4 c00 = {}, c01 = {}, c02 = {}, c03 = {};
    f32x4 c10 = {}, c11 = {}, c12 = {}, c13 = {};
    f32x4 c20 = {}, c21 = {}, c22 = {}, c23 = {};
    f32x4 c30 = {}, c31 = {}, c32 = {}, c33 = {};

    for (int k0 = 0; k0 < K; k0 += 64) {
#pragma unroll
        for (int i = 0; i < 8; ++i) { llds16(stp[i], stl[i]); stp[i] += 64; }
        __syncthreads();
#pragma unroll
        for (int kk = 0; kk < 2; ++kk) {
            int off = ((kk * 4 + quad) ^ sw) * 8;
            bf16x8 a0 = *(const bf16x8*)&As[(wm +  0 + lc) * 64 + off];
            bf16x8 a1 = *(const bf16x8*)&As[(wm + 16 + lc) * 64 + off];
            bf16x8 a2 = *(const bf16x8*)&As[(wm + 32 + lc) * 64 + off];
            bf16x8 a3 = *(const bf16x8*)&As[(wm + 48 + lc) * 64 + off];
            bf16x8 b0 = *(const bf16x8*)&Bs[(wn +  0 + lc) * 64 + off];
            bf16x8 b1 = *(const bf16x8*)&Bs[(wn + 16 + lc) * 64 + off];
            bf16x8 b2 = *(const bf16x8*)&Bs[(wn + 32 + lc) * 64 + off];
            bf16x8 b3 = *(const bf16x8*)&Bs[(wn + 48 + lc) * 64 + off];
            c00 = MFMA(a0, b0, c00, 0, 0, 0); c01 = MFMA(a0, b1, c01, 0, 0, 0);
            c02 = MFMA(a0, b2, c02, 0, 0, 0); c03 = MFMA(a0, b3, c03, 0, 0, 0);
            c10 = MFMA(a1, b0, c10, 0, 0, 0); c11 = MFMA(a1, b1, c11, 0, 0, 0);
            c12 = MFMA(a1, b2, c12, 0, 0, 0); c13 = MFMA(a1, b3, c13, 0, 0, 0);
            c20 = MFMA(a2, b0, c20, 0, 0, 0); c21 = MFMA(a2, b1, c21, 0, 0, 0);
            c22 = MFMA(a2, b2, c22, 0, 0, 0); c23 = MFMA(a2, b3, c23, 0, 0, 0);
            c30 = MFMA(a3, b0, c30, 0, 0, 0); c31 = MFMA(a3, b1, c31, 0, 0, 0);
            c32 = MFMA(a3, b2, c32, 0, 0, 0); c33 = MFMA(a3, b3, c33, 0, 0, 0);
        }
        __syncthreads();
    }

    int mb = m0 + wm + quad * 4, nb = n0 + wn + lc;
    st4<EPI>(c00, mb +  0, nb +  0, N, e); st4<EPI>(c01, mb +  0, nb + 16, N, e);
    st4<EPI>(c02, mb +  0, nb + 32, N, e); st4<EPI>(c03, mb +  0, nb + 48, N, e);
    st4<EPI>(c10, mb + 16, nb +  0, N, e); st4<EPI>(c11, mb + 16, nb + 16, N, e);
    st4<EPI>(c12, mb + 16, nb + 32, N, e); st4<EPI>(c13, mb + 16, nb + 48, N, e);
    st4<EPI>(c20, mb + 32, nb +  0, N, e); st4<EPI>(c21, mb + 32, nb + 16, N, e);
    st4<EPI>(c22, mb + 32, nb + 32, N, e); st4<EPI>(c23, mb + 32, nb + 48, N, e);
    st4<EPI>(c30, mb + 48, nb +  0, N, e); st4<EPI>(c31, mb + 48, nb + 16, N, e);
    st4<EPI>(c32, mb + 48, nb + 32, N, e); st4<EPI>(c33, mb + 48, nb + 48, N, e);
}

// ---------------- GEMM 64x128 tile (MLP1) ------------------------------------
template <int EPI>
__global__ __launch_bounds__(256, 2) void gemm_bt64(
    const ushort_t* __restrict__ A, const ushort_t* __restrict__ Bt,
    int M, int N, int K, EpiArgs e) {
    __shared__ ushort_t As[64 * 64];    // 8 KB
    __shared__ ushort_t Bs[128 * 64];   // 16 KB
    int m0 = blockIdx.x * 64, n0 = blockIdx.y * 128;
    int tid = threadIdx.x, wave = tid >> 6, lane = tid & 63;
    int quad = lane >> 4, lc = lane & 15;
    int wn = wave * 32;
    int srow = lane >> 3, sg = lane & 7;
    int sw = lc & 7;

    const ushort_t* stp[6];
    ushort_t* stl[6];
#pragma unroll
    for (int i = 0; i < 6; ++i) {
        int chunk = wave * 6 + i;
        if (chunk < 8) {
            int row = chunk * 8 + srow;
            stp[i] = A + (size_t)(m0 + row) * K + (sg ^ srow) * 8;
            stl[i] = &As[chunk * 512 + lane * 8];
        } else {
            int c = chunk - 8;
            int row = c * 8 + srow;
            stp[i] = Bt + (size_t)(n0 + row) * K + (sg ^ srow) * 8;
            stl[i] = &Bs[c * 512 + lane * 8];
        }
    }

    f32x4 c00 = {}, c01 = {};
    f32x4 c10 = {}, c11 = {};
    f32x4 c20 = {}, c21 = {};
    f32x4 c30 = {}, c31 = {};

    for (int k0 = 0; k0 < K; k0 += 64) {
#pragma unroll
        for (int i = 0; i < 6; ++i) { llds16(stp[i], stl[i]); stp[i] += 64; }
        __syncthreads();
#pragma unroll
        for (int kk = 0; kk < 2; ++kk) {
            int off = ((kk * 4 + quad) ^ sw) * 8;
            bf16x8 a0 = *(const bf16x8*)&As[( 0 + lc) * 64 + off];
            bf16x8 a1 = *(const bf16x8*)&As[(16 + lc) * 64 + off];
            bf16x8 a2 = *(const bf16x8*)&As[(32 + lc) * 64 + off];
            bf16x8 a3 = *(const bf16x8*)&As[(48 + lc) * 64 + off];
            bf16x8 b0 = *(const bf16x8*)&Bs[(wn +  0 + lc) * 64 + off];
            bf16x8 b1 = *(const bf16x8*)&Bs[(wn + 16 + lc) * 64 + off];
            c00 = MFMA(a0, b0, c00, 0, 0, 0); c01 = MFMA(a0, b1, c01, 0, 0, 0);
            c10 = MFMA(a1, b0, c10, 0, 0, 0); c11 = MFMA(a1, b1, c11, 0, 0, 0);
            c20 = MFMA(a2, b0, c20, 0, 0, 0); c21 = MFMA(a2, b1, c21, 0, 0, 0);
            c30 = MFMA(a3, b0, c30, 0, 0, 0); c31 = MFMA(a3, b1, c31, 0, 0, 0);
        }
        __syncthreads();
    }

    int mb = m0 + quad * 4, nb = n0 + wn + lc;
    st4<EPI>(c00, mb +  0, nb + 0, N, e); st4<EPI>(c01, mb +  0, nb + 16, N, e);
    st4<EPI>(c10, mb + 16, nb + 0, N, e); st4<EPI>(c11, mb + 16, nb + 16, N, e);
    st4<EPI>(c20, mb + 32, nb + 0, N, e); st4<EPI>(c21, mb + 32, nb + 16, N, e);
    st4<EPI>(c30, mb + 48, nb + 0, N, e); st4<EPI>(c31, mb + 48, nb + 16, N, e);
}

// ---------------- GEMM 32x128 tile (O-proj, MLP2: N=1024) --------------------
// N=1024 caps gemm_bt64 at grid 512 = 2 blocks/CU; R10/R11 paired runs show
// 4 blocks/CU beats 2 for this family (MLP1: bt64@1024blk > bt@512blk by
// 6-9 us) despite a worse LDS-read ratio. BM=32 doubles the grid to 1024 =
// 4 blocks/CU (LDS 20 KB, launch_bounds(256,4) caps VGPR<=128). B panels
// (<=4 MB) are L2-resident so the extra B re-reads are absorbed.
template <int EPI>
__global__ __launch_bounds__(256, 4) void gemm_bt32(
    const ushort_t* __restrict__ A, const ushort_t* __restrict__ Bt,
    int M, int N, int K, EpiArgs e) {
    __shared__ ushort_t As[32 * 64];    // 4 KB
    __shared__ ushort_t Bs[128 * 64];   // 16 KB
    int m0 = blockIdx.x * 32, n0 = blockIdx.y * 128;
    int tid = threadIdx.x, wave = tid >> 6, lane = tid & 63;
    int quad = lane >> 4, lc = lane & 15;
    int wn = wave * 32;
    int srow = lane >> 3, sg = lane & 7;
    int sw = lc & 7;

    const ushort_t* stp[5];
    ushort_t* stl[5];
#pragma unroll
    for (int i = 0; i < 5; ++i) {
        int chunk = wave * 5 + i;
        if (chunk < 4) {
            int row = chunk * 8 + srow;
            stp[i] = A + (size_t)(m0 + row) * K + (sg ^ srow) * 8;
            stl[i] = &As[chunk * 512 + lane * 8];
        } else {
            int c = chunk - 4;
            int row = c * 8 + srow;
            stp[i] = Bt + (size_t)(n0 + row) * K + (sg ^ srow) * 8;
            stl[i] = &Bs[c * 512 + lane * 8];
        }
    }

    f32x4 c00 = {}, c01 = {};
    f32x4 c10 = {}, c11 = {};

    for (int k0 = 0; k0 < K; k0 += 64) {
#pragma unroll
        for (int i = 0; i < 5; ++i) { llds16(stp[i], stl[i]); stp[i] += 64; }
        __syncthreads();
#pragma unroll
        for (int kk = 0; kk < 2; ++kk) {
            int off = ((kk * 4 + quad) ^ sw) * 8;
            bf16x8 a0 = *(const bf16x8*)&As[( 0 + lc) * 64 + off];
            bf16x8 a1 = *(const bf16x8*)&As[(16 + lc) * 64 + off];
            bf16x8 b0 = *(const bf16x8*)&Bs[(wn +  0 + lc) * 64 + off];
            bf16x8 b1 = *(const bf16x8*)&Bs[(wn + 16 + lc) * 64 + off];
            c00 = MFMA(a0, b0, c00, 0, 0, 0); c01 = MFMA(a0, b1, c01, 0, 0, 0);
            c10 = MFMA(a1, b0, c10, 0, 0, 0); c11 = MFMA(a1, b1, c11, 0, 0, 0);
        }
        __syncthreads();
    }

    int mb = m0 + quad * 4, nb = n0 + wn + lc;
    st4<EPI>(c00, mb +  0, nb + 0, N, e); st4<EPI>(c01, mb +  0, nb + 16, N, e);
    st4<EPI>(c10, mb + 16, nb + 0, N, e); st4<EPI>(c11, mb + 16, nb + 16, N, e);
}

// ---------------- flash attention v14 (best measured): 8-wave, single buf ----
__global__ __launch_bounds__(512, 4) void attn(
    const ushort_t* __restrict__ Q, const ushort_t* __restrict__ Kx,
    const ushort_t* __restrict__ Vt, ushort_t* __restrict__ O) {
    __shared__ ushort_t Ks[128 * 64];     // 16 KB
    __shared__ ushort_t Vs[64 * 128];     // 16 KB
    int id = blockIdx.x;
    int bh = ((id & 7) << 2) + ((id >> 3) & 3);  // 4 bh per XCD class
    int qt = id >> 5;                            // 16 q-tiles of 128 rows
    const ushort_t* Qg = Q + ((size_t)bh * L_ + qt * 128) * DH_;
    const ushort_t* Kg = Kx + (size_t)bh * L_ * DH_;
    const ushort_t* Vg = Vt + (size_t)bh * DH_ * L_;
    int tid = threadIdx.x, wave = tid >> 6, lane = tid & 63;
    int quad = lane >> 4, lc = lane & 15;
    int sw = lc & 7;
    int srow = lane >> 3, sg = lane & 7;

    const ushort_t* stp[4];
    ushort_t* stl[4];
    int stinc;
    if (wave < 4) {
        stinc = 128 * DH_;
#pragma unroll
        for (int i = 0; i < 4; ++i) {
            int chunk = wave * 4 + i;            // 0..15
            int slot = chunk * 8 + srow;         // LDS row (slot)
            int s5 = slot & 31;                  // within-32 position
            int sig = (slot & ~31) + ((s5 & 15) >> 2) * 8 + (s5 & 3) + (s5 >> 4) * 4;
            stp[i] = Kg + (size_t)sig * DH_ + (sg ^ srow) * 8;
            stl[i] = &Ks[chunk * 512 + lane * 8];
        }
    } else {
        stinc = 128;
#pragma unroll
        for (int i = 0; i < 4; ++i) {
            int c2 = (wave - 4) * 4 + i;         // 0..15
            int row = c2 * 4 + (lane >> 4);
            int g = (lane & 15) ^ (row & 15);
            stp[i] = Vg + (size_t)row * L_ + g * 8;
            stl[i] = &Vs[c2 * 512 + lane * 8];
        }
    }

    const ushort_t* qp = Qg + (size_t)(wave * 16 + lc) * DH_ + quad * 8;
    bf16x8 q0 = *(const bf16x8*)(qp);        // kk0: dh 0..31 (quad-sliced)
    bf16x8 q1 = *(const bf16x8*)(qp + 32);   // kk1: dh 32..63

    union { u32 u[4]; bf16x8 v; } ones;
    ones.u[0] = ones.u[1] = ones.u[2] = ones.u[3] = 0x3F803F80u;

    f32x4 o0 = {}, o1 = {}, o2 = {}, o3 = {};
    f32x4 osum = {};   // rowsum accumulator (cols redundant)

    for (int t = 0; t < 16; ++t) {
#pragma unroll
        for (int i = 0; i < 4; ++i) { llds16(stp[i], stl[i]); stp[i] += stinc; }
        __syncthreads();

        f32x4 s[8];
        __builtin_amdgcn_s_setprio(1);
#pragma unroll
        for (int kk = 0; kk < 2; ++kk) {
            int off = ((kk * 4 + quad) ^ sw) * 8;
            bf16x8 aq = kk == 0 ? q0 : q1;
#pragma unroll
            for (int ni = 0; ni < 8; ++ni) {
                bf16x8 bk = *(const bf16x8*)&Ks[(ni * 16 + lc) * 64 + off];
                if (kk == 0) {
                    f32x4 z = {0.f, 0.f, 0.f, 0.f};
                    s[ni] = MFMA(bk, aq, z, 0, 0, 0);
                } else {
                    s[ni] = MFMA(bk, aq, s[ni], 0, 0, 0);
                }
            }
        }
        __builtin_amdgcn_s_setprio(0);

        u32 px[8], py[8];
#pragma unroll
        for (int ni = 0; ni < 8; ++ni) {
            float p0 = __builtin_amdgcn_exp2f(s[ni][0]);
            float p1 = __builtin_amdgcn_exp2f(s[ni][1]);
            float p2 = __builtin_amdgcn_exp2f(s[ni][2]);
            float p3 = __builtin_amdgcn_exp2f(s[ni][3]);
            px[ni] = pk_bf16(p0, p1);
            py[ni] = pk_bf16(p2, p3);
        }

        __builtin_amdgcn_s_setprio(1);
#pragma unroll
        for (int kk = 0; kk < 4; ++kk) {
            int gq = kk * 4 + quad;
            bf16x8 bv0 = *(const bf16x8*)&Vs[( 0 + lc) * 128 + ((gq ^ lc) * 8)];
            bf16x8 bv1 = *(const bf16x8*)&Vs[(16 + lc) * 128 + ((gq ^ lc) * 8)];
            bf16x8 bv2 = *(const bf16x8*)&Vs[(32 + lc) * 128 + ((gq ^ lc) * 8)];
            bf16x8 bv3 = *(const bf16x8*)&Vs[(48 + lc) * 128 + ((gq ^ lc) * 8)];
            union { u32 u[4]; bf16x8 v; } a;
            a.u[0] = px[2 * kk]; a.u[1] = py[2 * kk];
            a.u[2] = px[2 * kk + 1]; a.u[3] = py[2 * kk + 1];
            o0 = MFMA(a.v, bv0, o0, 0, 0, 0); o1 = MFMA(a.v, bv1, o1, 0, 0, 0);
            o2 = MFMA(a.v, bv2, o2, 0, 0, 0); o3 = MFMA(a.v, bv3, o3, 0, 0, 0);
            osum = MFMA(a.v, ones.v, osum, 0, 0, 0);
        }
        __builtin_amdgcn_s_setprio(0);
        __syncthreads();  // Ks/Vs consumed before next tile's staging
    }

    f32x4 inv;
#pragma unroll
    for (int r = 0; r < 4; ++r) inv[r] = 1.f / osum[r];
#pragma unroll
    for (int nio = 0; nio < 4; ++nio) {
        const f32x4& ov = nio == 0 ? o0 : nio == 1 ? o1 : nio == 2 ? o2 : o3;
#pragma unroll
        for (int r = 0; r < 4; ++r) {
            int row = qt * 128 + wave * 16 + quad * 4 + r;
            O[((size_t)bh * L_ + row) * DH_ + nio * 16 + lc] = f2bf(ov[r] * inv[r]);
        }
    }
}

// -----------------------------------------------------------------------------
extern "C" void kernel_launch(void* const* d_in, const int* in_sizes, int n_in,
                              void* d_out, int out_size, void* d_ws, size_t ws_size,
                              hipStream_t stream) {
    (void)in_sizes; (void)n_in; (void)out_size; (void)ws_size;
    const float* x    = (const float*)d_in[0];
    const float* c    = (const float*)d_in[1];
    const float* Wq   = (const float*)d_in[2];
    const float* bq   = (const float*)d_in[3];
    const float* Wk   = (const float*)d_in[4];
    const float* bk   = (const float*)d_in[5];
    const float* Wv   = (const float*)d_in[6];
    const float* bv   = (const float*)d_in[7];
    const float* Wo   = (const float*)d_in[8];
    const float* bo   = (const float*)d_in[9];
    const float* W1   = (const float*)d_in[10];
    const float* b1   = (const float*)d_in[11];
    const float* W2   = (const float*)d_in[12];
    const float* b2   = (const float*)d_in[13];
    const float* Wada = (const float*)d_in[14];
    const float* bada = (const float*)d_in[15];

    char* w = (char*)d_ws;
    float*    ada  = (float*)(w + 0);                     // 49152 B
    ushort_t* Wqkv = (ushort_t*)(w + 49152);              // 6 MiB
    ushort_t* Wo_t = (ushort_t*)(w + 6340608);            // 2 MiB
    ushort_t* W1_t = (ushort_t*)(w + 8437760);            // 4 MiB
    ushort_t* W2_t = (ushort_t*)(w + 12632064);           // 4 MiB
    ushort_t* h    = (ushort_t*)(w + 16826368);           // 8 MiB (h / h2)
    ushort_t* Qb   = (ushort_t*)(w + 25214976);           // 8 MiB (Q)
    ushort_t* Kb   = (ushort_t*)(w + 33603584);           // 8 MiB (K)
    ushort_t* Ob   = (ushort_t*)(w + 41992192);           // 8 MiB (final O)
    ushort_t* Vtb  = (ushort_t*)(w + 50380800);           // 8 MiB (ada partials, then V^T)
    float*    x1   = (float*)(w + 58769408);              // 16 MiB (x1)
    ushort_t* m1   = Qb;            // MLP hidden (16 MiB = Qb+Kb, dead post-attn)
    float*    adap = (float*)Vtb;   // 786 KB split-k partials; dead before QKV gemm

    const int M = B_ * L_;  // 4096

    transpose_w_all<<<2048, 256, 0, stream>>>(Wq, Wk, Wv, Wo, W1, W2,
                                              Wqkv, Wo_t, W1_t, W2_t);

    ada_gemv<<<dim3(24, 16), 256, 0, stream>>>(c, Wada, adap);
    ada_reduce<<<24, 256, 0, stream>>>(adap, bada, ada);
    ln_mod<<<M, 256, 0, stream>>>(x, ada, 0, 1024, h);

    // QKV: Q,K -> (B,H,L,DH); V -> V^T (BH,DH,L) directly (transpose_v fused)
    EpiArgs e0 = {bq, bk, bv, Qb, Kb, Vtb, nullptr, nullptr, nullptr};
    gemm_bt<0><<<dim3(32, 24), 256, 0, stream>>>(h, Wqkv, M, 3072, D_, e0);

    // full-KV attention: final O, no partials, no merge; 8-wave blocks
    attn<<<512, 512, 0, stream>>>(Qb, Kb, Vtb, Ob);

    // O-proj (N=1024): 32x128 tile, grid (128,8) = 1024 blocks = 4/CU
    EpiArgs e1 = {bo, nullptr, nullptr, nullptr, nullptr, nullptr, x, ada + 2048, x1};
    gemm_bt32<2><<<dim3(128, 8), 256, 0, stream>>>(Ob, Wo_t, M, D_, D_, e1);

    ln_mod<<<M, 256, 0, stream>>>(x1, ada, 3072, 4096, h);

    // MLP1 (N=2048): 64x128 tile, grid (64,16) = 1024 blocks = 4/CU (R6-best)
    EpiArgs e2 = {b1, nullptr, nullptr, m1, nullptr, nullptr, nullptr, nullptr, nullptr};
    gemm_bt64<1><<<dim3(64, 16), 256, 0, stream>>>(h, W1_t, M, FF_, D_, e2);

    // MLP2 (N=1024): 32x128 tile, grid (128,8) = 1024 blocks = 4/CU
    EpiArgs e3 = {b2, nullptr, nullptr, nullptr, nullptr, nullptr, x1, ada + 5120, (float*)d_out};
    gemm_bt32<2><<<dim3(128, 8), 256, 0, stream>>>(m1, W2_t, M, D_, FF_, e3);
}